// Round 17
// baseline (367.345 us; speedup 1.0000x reference)
//
#include <hip/hip_runtime.h>

typedef _Float16 f16;
typedef __attribute__((ext_vector_type(4))) _Float16 half4;
typedef __attribute__((ext_vector_type(8))) _Float16 half8;
typedef __attribute__((ext_vector_type(4))) float f32x4;
typedef unsigned short u16;

#define MFMA32(a,b,c) __builtin_amdgcn_mfma_f32_16x16x32_f16(a,b,c,0,0,0)
#define MFMA16(a,b,c) __builtin_amdgcn_mfma_f32_16x16x16f16(a,b,c,0,0,0)

// ws layout (f16 element offsets)
#define W_IN0   0
#define W_OUT0  196608
#define W_PROJ0 262144
#define X0      327680
#define QK0     33882112ull
#define VT0     100990976ull

// exact-grade GELU: erf via A&S 7.1.26 (|eps|<=1.5e-7)
__device__ __forceinline__ float gelu_f(float x) {
    float z = x * 0.70710678118f;
    float az = fabsf(z);
    float t = 1.f / (1.f + 0.3275911f * az);
    float e = __expf(-z * z);
    float poly = ((((1.061405429f * t - 1.453152027f) * t + 1.421413741f) * t
                   - 0.284496736f) * t + 0.254829592f) * t;
    float er = 1.f - poly * e;
    er = copysignf(er, z);
    return 0.5f * x * (1.f + er);
}

// ---------------- k0: cast weights to f16; build k2-geometry images for w_out/w_proj ----
// Image per matrix: [ch:8][kc:8][row r:32][slot:4] 16B frags; slot = g ^ ((r>>1)&3).
// Frag (ch,kc,r,g) = [W[ch*32+r][kc*32+g*4..+3], W[..][kc*32+16+g*4..+3]] (MFMA32 A-frag).
// k3 stages chunks linearly (gload_lds) and reads base+kc*2048+c*64+(g^((c>>1)&3))*16:
// contiguous 1024B per wave per kc, 2 lanes/bank = free (k2's measured-0 pattern).
__global__ void k0_cast(const float* __restrict__ iw, const float* __restrict__ ow,
                        const float* __restrict__ pw, f16* __restrict__ W) {
    int i = blockIdx.x * 256 + threadIdx.x;
    if (i < 196608) W[W_IN0 + i] = (f16)iw[i];
    if (i < 16384) {
        const int s = i & 8191;
        const float* src = (i < 8192) ? ow : pw;
        f16* dst = W + ((i < 8192) ? W_OUT0 : W_PROJ0);
        const int g  = s & 3;
        const int r  = (s >> 2) & 31;
        const int kc = (s >> 7) & 7;
        const int ch = s >> 10;
        const int R = ch * 32 + r;
        const int c0 = kc * 32 + g * 4;
        f32x4 v0 = *(const f32x4*)(src + R * 256 + c0);
        f32x4 v1 = *(const f32x4*)(src + R * 256 + c0 + 16);
        half8 o;
#pragma unroll
        for (int j = 0; j < 4; ++j) { o[j] = (f16)v0[j]; o[j + 4] = (f16)v1[j]; }
        const int sg = g ^ ((r >> 1) & 3);
        *(half8*)(dst + ch * 8192 + kc * 1024 + r * 32 + sg * 8) = o;
    }
}

// ---------------- k1: NCHW gather + LayerNorm -> X[t][256] f16 (no LDS, float4 loads) ----------------
// R16->R17: launch_bounds (256,4)->(256,2). At (256,4) the 128-reg budget + occupancy
// heuristic pinned arch VGPR at 64 < the ~110-reg payload -> scratch spill (VGPR_Count 64,
// WRITE 118MB vs 67 ideal). Budget 256 removes the spill; VGPR-implied occupancy still
// ~4 waves/SIMD. Do NOT tighten k1's bounds again.
__global__ __launch_bounds__(256, 2)
void k1_pack(const float* __restrict__ feat, const float* __restrict__ lnw,
             const float* __restrict__ lnb, f16* __restrict__ X) {
    const int tid = threadIdx.x, lane = tid & 63, hh = tid >> 6;
    const int bid = blockIdx.x;
    const int jh = bid & 3, wi = (bid >> 2) & 31, bb = bid >> 7;
    const int h0 = wi * 4, w0 = jh * 32;
    const int wl4 = lane & 7, cg = lane >> 3;
    const int h = h0 + hh, wb = w0 + wl4 * 4;
    const bool hok = (h < 127);
    const bool edge = (wb + 3) >= 127;      // only jh==3 && wl4==7 (w=127 is pad)
    const size_t bbase = (size_t)bb * (256 * 127 * 127);
    const int c0 = cg * 32;
    const float* p0 = feat + bbase + (size_t)c0 * 16129 + (size_t)h * 127 + wb;

    half4 arr[32];                           // [ch within group][token e], f16 pre-LN
    float ss[4] = {0.f, 0.f, 0.f, 0.f}, qq[4] = {0.f, 0.f, 0.f, 0.f};
    if (hok && !edge) {
#pragma unroll
        for (int i = 0; i < 32; ++i) {
            f32x4 v = *(const f32x4*)(p0 + (size_t)i * 16129);
            half4 hv;
#pragma unroll
            for (int e = 0; e < 4; ++e) { ss[e] += v[e]; qq[e] += v[e] * v[e]; hv[e] = (f16)v[e]; }
            arr[i] = hv;
        }
    } else if (hok) {
#pragma unroll
        for (int i = 0; i < 32; ++i) {
            const float* pi = p0 + (size_t)i * 16129;
            half4 hv;
#pragma unroll
            for (int e = 0; e < 3; ++e) { float v = pi[e]; ss[e] += v; qq[e] += v * v; hv[e] = (f16)v; }
            hv[3] = (f16)0.f;
            arr[i] = hv;
        }
    } else {
#pragma unroll
        for (int i = 0; i < 32; ++i) {
            half4 hv; hv[0] = hv[1] = hv[2] = hv[3] = (f16)0.f; arr[i] = hv;
        }
    }
#pragma unroll
    for (int e = 0; e < 4; ++e) {
        ss[e] += __shfl_xor(ss[e], 8);  qq[e] += __shfl_xor(qq[e], 8);
        ss[e] += __shfl_xor(ss[e], 16); qq[e] += __shfl_xor(qq[e], 16);
        ss[e] += __shfl_xor(ss[e], 32); qq[e] += __shfl_xor(qq[e], 32);
    }
    float mu[4], rs[4];
#pragma unroll
    for (int e = 0; e < 4; ++e) {
        mu[e] = ss[e] * (1.f / 256.f);
        rs[e] = rsqrtf(qq[e] * (1.f / 256.f) - mu[e] * mu[e] + 1e-5f);
    }
#pragma unroll
    for (int q = 0; q < 4; ++q) {
        f32x4 lw0 = *(const f32x4*)(lnw + c0 + q * 8);
        f32x4 lw1 = *(const f32x4*)(lnw + c0 + q * 8 + 4);
        f32x4 lb0 = *(const f32x4*)(lnb + c0 + q * 8);
        f32x4 lb1 = *(const f32x4*)(lnb + c0 + q * 8 + 4);
#pragma unroll
        for (int e = 0; e < 4; ++e) {
            const int m = wl4 * 16 + hh * 4 + e;
            f16* xrow = X + ((size_t)bid * 128 + m) * 256 + c0;
            half8 o;
#pragma unroll
            for (int j = 0; j < 4; ++j) {
                o[j]     = (f16)(((float)arr[q * 8 + j][e]     - mu[e]) * rs[e] * lw0[j] + lb0[j]);
                o[j + 4] = (f16)(((float)arr[q * 8 + j + 4][e] - mu[e]) * rs[e] * lw1[j] + lb1[j]);
            }
            *(half8*)(xrow + q * 8) = o;
        }
    }
}

// ---------------- k2: QKV GEMM  X[131072x256] @ in_w^T -> QK / VT ----------------
// Frozen at R13 best (BM=256, 8 waves, BK=32, involution staging; VGPR-bound at 2 blk/CU).
__global__ __launch_bounds__(512, 2)
void k2_qkv(const f16* __restrict__ X, const f16* __restrict__ win,
            const float* __restrict__ inb, f16* __restrict__ QK, f16* __restrict__ VT) {
    __shared__ __align__(16) char sm[49152];   // 2 bufs x (A 16K | B 8K)
    const int tid = threadIdx.x, lane = tid & 63, wv = tid >> 6;   // 8 waves
    const int nwg = gridDim.x;                 // 3072, divisible by 8
    const int bid = (blockIdx.x & 7) * (nwg >> 3) + (blockIdx.x >> 3);
    const int mt = bid / 6, nb = bid % 6;
    const size_t Mbase = (size_t)mt * 256;
    const int n0 = nb * 128;
    const int wm = wv >> 1, wn = wv & 1;       // 4 M-groups x 2 N-groups
    const int c = lane & 15, g = lane >> 4;
    const int chs = (lane & 3) ^ ((lane >> 3) & 3);   // involution source chunk

    f32x4 acc[4][4];
#pragma unroll
    for (int a = 0; a < 4; ++a)
#pragma unroll
        for (int b = 0; b < 4; ++b) acc[a][b] = f32x4{0.f, 0.f, 0.f, 0.f};

    auto stage = [&](int step, int bsel) {
        const f16* As = X + Mbase * 256 + step * 32;
        const f16* Bs = win + (size_t)n0 * 256 + step * 32;
        char* base = sm + bsel * 24576;
#pragma unroll
        for (int p = 0; p < 2; ++p) {
            int row = p * 128 + wv * 16 + (lane >> 2);
            __builtin_amdgcn_global_load_lds(
                (const __attribute__((address_space(1))) unsigned int*)(As + (size_t)row * 256 + chs * 8),
                (__attribute__((address_space(3))) unsigned int*)(base + p * 8192 + wv * 1024),
                16, 0, 0);
        }
        {
            int row = wv * 16 + (lane >> 2);
            __builtin_amdgcn_global_load_lds(
                (const __attribute__((address_space(1))) unsigned int*)(Bs + (size_t)row * 256 + chs * 8),
                (__attribute__((address_space(3))) unsigned int*)(base + 16384 + wv * 1024),
                16, 0, 0);
        }
    };
    const int rsl = (g ^ ((c >> 1) & 3)) * 16;   // swizzled 16B slot within 64B row
    auto compute = [&](int bsel) {
        char* base = sm + bsel * 24576;
        half8 a[4], b[4];
#pragma unroll
        for (int mi = 0; mi < 4; ++mi) {
            int row = wm * 64 + mi * 16 + c;
            a[mi] = *(half8*)(base + row * 64 + rsl);
        }
#pragma unroll
        for (int nt = 0; nt < 4; ++nt) {
            int row = wn * 64 + nt * 16 + c;
            b[nt] = *(half8*)(base + 16384 + row * 64 + rsl);
        }
#pragma unroll
        for (int mi = 0; mi < 4; ++mi)
#pragma unroll
            for (int nt = 0; nt < 4; ++nt)
                acc[mi][nt] = MFMA32(a[mi], b[nt], acc[mi][nt]);
    };

    stage(0, 0);
    __syncthreads();
#pragma unroll
    for (int s = 0; s < 8; ++s) {
        const int bsel = s & 1;
        if (s < 7) stage(s + 1, bsel ^ 1);
        compute(bsel);
        __syncthreads();
    }

    const f32x4 z4 = {0.f, 0.f, 0.f, 0.f};
    half4 idf;
#pragma unroll
    for (int j = 0; j < 4; ++j) idf[j] = (f16)((g * 4 + j == c) ? 1.f : 0.f);

    if (n0 < 512) {
        // Q,K: transpose via identity mfma, store row-major QK[t][512]
#pragma unroll
        for (int mi = 0; mi < 4; ++mi)
#pragma unroll
            for (int nt = 0; nt < 4; ++nt) {
                int n = n0 + wn * 64 + nt * 16 + c;
                float bias = inb[n];
                half4 h;
#pragma unroll
                for (int r = 0; r < 4; ++r) h[r] = (f16)(acc[mi][nt][r] + bias);
                f32x4 t = MFMA16(h, idf, z4);      // C/D-as-A (=T^T) times I -> transposed tile
                half4 o;
#pragma unroll
                for (int r = 0; r < 4; ++r) o[r] = (f16)t[r];
                size_t tok = Mbase + wm * 64 + mi * 16 + c;       // col of transposed tile = m
                *(half4*)(QK + tok * 512 + (n0 + wn * 64 + nt * 16 + g * 4)) = o;
            }
    } else {
        // V: store [win][d][t] directly from C/D (rows = 4 contiguous tokens)
#pragma unroll
        for (int mi = 0; mi < 4; ++mi)
#pragma unroll
            for (int nt = 0; nt < 4; ++nt) {
                int n = n0 + wn * 64 + nt * 16 + c;
                float bias = inb[n];
                half4 h;
#pragma unroll
                for (int r = 0; r < 4; ++r) h[r] = (f16)(acc[mi][nt][r] + bias);
                int d = n - 512;
                size_t tokb = Mbase + wm * 64 + mi * 16;          // window-aligned
                size_t winI = tokb >> 4;
                *(half4*)(VT + winI * 4096 + (size_t)d * 16 + g * 4) = h;
            }
    }
}

// ---------------- k3: attention + out-proj + proj + GELU -> G[t][256] f16 ----------------
// Frozen at R16 (LDS-staged, k2-geometry conflict-free image, poly-GELU, lb(256,3)).
__global__ __launch_bounds__(256, 3)
void k3_attn(const f16* __restrict__ QK, const f16* __restrict__ VT,
             const f16* __restrict__ wout, const f16* __restrict__ wproj,
             const float* __restrict__ outb, const float* __restrict__ projb,
             f16* __restrict__ G) {
    __shared__ __align__(16) char sm[32768];   // 2 x 16KB weight chunks (k2-geometry image)
    const int tid = threadIdx.x, lane = tid & 63, wv = tid >> 6;   // 4 waves
    const int c = lane & 15, g = lane >> 4;
    const size_t win = (size_t)blockIdx.x * 4 + wv;
    const f16* qrow = QK + (win * 16 + c) * 512;
    const f32x4 z4 = {0.f, 0.f, 0.f, 0.f};

    auto stageW = [&](const f16* img, int rc, int bsel) {
#pragma unroll
        for (int q2 = 0; q2 < 4; ++q2) {
            int ia = wv * 4 + q2;
            __builtin_amdgcn_global_load_lds(
                (const __attribute__((address_space(1))) unsigned int*)(img + rc * 8192 + ia * 512 + lane * 8),
                (__attribute__((address_space(3))) unsigned int*)(sm + bsel * 16384 + ia * 1024),
                16, 0, 0);
        }
    };

    stageW(wout, 0, 0);   // chunk 0 in flight under attention

    // ---- attention, all in registers; pack PV outputs as MFMA32 B-frags ofp[hq][t] ----
    half8 ofp[4][2];
#pragma unroll
    for (int hq = 0; hq < 4; ++hq) {
        half8 af0 = *(const half8*)(qrow + 256 + hq * 64 + g * 8);
        half8 af1 = *(const half8*)(qrow + 256 + hq * 64 + 32 + g * 8);
        half8 bq0 = *(const half8*)(qrow + hq * 64 + g * 8);
        half8 bq1 = *(const half8*)(qrow + hq * 64 + 32 + g * 8);
        f32x4 sacc = MFMA32(af0, bq0, z4);     // S^T[k_tok][q]
        sacc = MFMA32(af1, bq1, sacc);
        float s0 = sacc[0] * 0.125f, s1 = sacc[1] * 0.125f;
        float s2 = sacc[2] * 0.125f, s3 = sacc[3] * 0.125f;
        float mx = fmaxf(fmaxf(s0, s1), fmaxf(s2, s3));
        mx = fmaxf(mx, __shfl_xor(mx, 16));
        mx = fmaxf(mx, __shfl_xor(mx, 32));
        float p0 = __expf(s0 - mx), p1 = __expf(s1 - mx);
        float p2 = __expf(s2 - mx), p3 = __expf(s3 - mx);
        float sum = p0 + p1 + p2 + p3;
        sum += __shfl_xor(sum, 16);
        sum += __shfl_xor(sum, 32);
        float inv = 1.f / sum;
        half4 pf;
        pf[0] = (f16)(p0 * inv); pf[1] = (f16)(p1 * inv);
        pf[2] = (f16)(p2 * inv); pf[3] = (f16)(p3 * inv);
#pragma unroll
        for (int nt = 0; nt < 4; ++nt) {
            half4 vf = *(const half4*)(VT + win * 4096 + (size_t)(hq * 64 + nt * 16 + c) * 16 + g * 4);
            f32x4 o = MFMA16(vf, pf, z4);      // O^T[d][q]
#pragma unroll
            for (int r = 0; r < 4; ++r) ofp[hq][nt >> 1][(nt & 1) * 4 + r] = (f16)o[r];
        }
    }

    const int rsl = (g ^ ((c >> 1) & 3)) * 16;   // intra-row rotated 16B slot (k2 pattern)
    half8 obp[8];
    __syncthreads();

    // ---- out-proj: per 32-row weight chunk, 8 kc of 32 via MFMA32 ----
#pragma unroll
    for (int ch = 0; ch < 8; ++ch) {
        if (ch < 7) stageW(wout, ch + 1, (ch + 1) & 1);
        else        stageW(wproj, 0, (ch + 1) & 1);
        char* base = sm + (ch & 1) * 16384;
        f32x4 a0 = z4, a1 = z4;
#pragma unroll
        for (int kc = 0; kc < 8; ++kc) {
            half8 w0 = *(half8*)(base + kc * 2048 + c * 64 + rsl);
            a0 = MFMA32(w0, ofp[kc >> 1][kc & 1], a0);
            half8 w1 = *(half8*)(base + kc * 2048 + 1024 + c * 64 + rsl);
            a1 = MFMA32(w1, ofp[kc >> 1][kc & 1], a1);
        }
        f32x4 b0 = *(const f32x4*)(outb + ch * 32 + g * 4);
        f32x4 b1 = *(const f32x4*)(outb + ch * 32 + 16 + g * 4);
#pragma unroll
        for (int r = 0; r < 4; ++r) {
            obp[ch][r]     = (f16)(a0[r] + b0[r]);
            obp[ch][4 + r] = (f16)(a1[r] + b1[r]);
        }
        __syncthreads();
    }

    // ---- proj + bias + exact-grade GELU + store G ----
#pragma unroll
    for (int pc = 0; pc < 8; ++pc) {
        if (pc < 7) stageW(wproj, pc + 1, (pc + 1) & 1);
        char* base = sm + (pc & 1) * 16384;
        f32x4 a0 = z4, a1 = z4;
#pragma unroll
        for (int kc = 0; kc < 8; ++kc) {
            half8 w0 = *(half8*)(base + kc * 2048 + c * 64 + rsl);
            a0 = MFMA32(w0, obp[kc], a0);
            half8 w1 = *(half8*)(base + kc * 2048 + 1024 + c * 64 + rsl);
            a1 = MFMA32(w1, obp[kc], a1);
        }
        f32x4 b0 = *(const f32x4*)(projb + pc * 32 + g * 4);
        f32x4 b1 = *(const f32x4*)(projb + pc * 32 + 16 + g * 4);
        half4 h0, h1;
#pragma unroll
        for (int r = 0; r < 4; ++r) {
            h0[r] = (f16)gelu_f(a0[r] + b0[r]);
            h1[r] = (f16)gelu_f(a1[r] + b1[r]);
        }
        f16* grow = G + (win * 16 + c) * 256 + pc * 32;
        *(half4*)(grow + g * 4) = h0;
        *(half4*)(grow + 16 + g * 4) = h1;
        if (pc < 7) __syncthreads();
    }
}

// ---------------- k4: residual + NCHW scatter, one block per full (bb,h) row ----------------
__global__ __launch_bounds__(256, 8)
void k4_out(const f16* __restrict__ G, const float* __restrict__ feat, float* __restrict__ outp) {
    const int tid = threadIdx.x;
    const int bid = blockIdx.x;            // bb*127 + h
    const int bb = bid / 127, h = bid % 127;
    const int w = tid & 127;               // 0..127 (w==127 masked: pad column)
    const int cq = tid >> 7;               // 0..1
    const bool wok = (w < 127);
    const size_t bbase = (size_t)bb * (256 * 127 * 127);
    const int wi = h >> 2, hh = h & 3;
    const int jh = w >> 5, wl4 = (w >> 2) & 7, e = w & 3;
    const size_t t = ((size_t)((bb * 32 + wi) * 4 + jh)) * 128 + wl4 * 16 + hh * 4 + e;
    const f16* gp = G + t * 256;
    const float* fp = feat + bbase + (size_t)h * 127 + w;
    float* op = outp + bbase + (size_t)h * 127 + w;
#pragma unroll 4
    for (int ci = 0; ci < 32; ++ci) {
        const int ch = ci * 8 + cq * 4;
        if (wok) {
            half4 g4 = *(const half4*)(gp + ch);
#pragma unroll
            for (int j = 0; j < 4; ++j) {
                size_t off = (size_t)(ch + j) * 16129;
                op[off] = fp[off] + (float)g4[j];
            }
        }
    }
}

extern "C" void kernel_launch(void* const* d_in, const int* in_sizes, int n_in,
                              void* d_out, int out_size, void* d_ws, size_t ws_size,
                              hipStream_t stream) {
    const float* feat   = (const float*)d_in[0];
    const float* ln_w   = (const float*)d_in[1];
    const float* ln_b   = (const float*)d_in[2];
    const float* in_w   = (const float*)d_in[3];
    const float* in_b   = (const float*)d_in[4];
    const float* out_w  = (const float*)d_in[5];
    const float* out_b  = (const float*)d_in[6];
    const float* proj_w = (const float*)d_in[7];
    const float* proj_b = (const float*)d_in[8];

    f16* W  = (f16*)d_ws;
    f16* Xb  = W + X0;
    f16* QKb = W + QK0;
    f16* VTb = W + VT0;
    f16* Gb  = Xb;   // reuse X region for G (X dead after k2)

    k0_cast<<<768, 256, 0, stream>>>(in_w, out_w, proj_w, W);
    k1_pack<<<1024, 256, 0, stream>>>(feat, ln_w, ln_b, Xb);
    k2_qkv<<<3072, 512, 0, stream>>>(Xb, W + W_IN0, in_b, QKb, VTb);
    k3_attn<<<2048, 256, 0, stream>>>(QKb, VTb, W + W_OUT0, W + W_PROJ0, out_b, proj_b, Gb);
    k4_out<<<1016, 256, 0, stream>>>(Gb, feat, (float*)d_out);
}

// Round 18
// 340.269 us; speedup vs baseline: 1.0796x; 1.0796x over previous
//
#include <hip/hip_runtime.h>

typedef _Float16 f16;
typedef __attribute__((ext_vector_type(4))) _Float16 half4;
typedef __attribute__((ext_vector_type(8))) _Float16 half8;
typedef __attribute__((ext_vector_type(4))) float f32x4;
typedef unsigned short u16;

#define MFMA32(a,b,c) __builtin_amdgcn_mfma_f32_16x16x32_f16(a,b,c,0,0,0)
#define MFMA16(a,b,c) __builtin_amdgcn_mfma_f32_16x16x16f16(a,b,c,0,0,0)

// ws layout (f16 element offsets)
#define W_IN0   0
#define W_OUT0  196608
#define W_PROJ0 262144
#define X0      327680
#define QK0     33882112ull
#define VT0     100990976ull

// exact-grade GELU: erf via A&S 7.1.26 (|eps|<=1.5e-7)
__device__ __forceinline__ float gelu_f(float x) {
    float z = x * 0.70710678118f;
    float az = fabsf(z);
    float t = 1.f / (1.f + 0.3275911f * az);
    float e = __expf(-z * z);
    float poly = ((((1.061405429f * t - 1.453152027f) * t + 1.421413741f) * t
                   - 0.284496736f) * t + 0.254829592f) * t;
    float er = 1.f - poly * e;
    er = copysignf(er, z);
    return 0.5f * x * (1.f + er);
}

// ---------------- k0: cast weights to f16; build k2-geometry images for w_out/w_proj ----
__global__ void k0_cast(const float* __restrict__ iw, const float* __restrict__ ow,
                        const float* __restrict__ pw, f16* __restrict__ W) {
    int i = blockIdx.x * 256 + threadIdx.x;
    if (i < 196608) W[W_IN0 + i] = (f16)iw[i];
    if (i < 16384) {
        const int s = i & 8191;
        const float* src = (i < 8192) ? ow : pw;
        f16* dst = W + ((i < 8192) ? W_OUT0 : W_PROJ0);
        const int g  = s & 3;
        const int r  = (s >> 2) & 31;
        const int kc = (s >> 7) & 7;
        const int ch = s >> 10;
        const int R = ch * 32 + r;
        const int c0 = kc * 32 + g * 4;
        f32x4 v0 = *(const f32x4*)(src + R * 256 + c0);
        f32x4 v1 = *(const f32x4*)(src + R * 256 + c0 + 16);
        half8 o;
#pragma unroll
        for (int j = 0; j < 4; ++j) { o[j] = (f16)v0[j]; o[j + 4] = (f16)v1[j]; }
        const int sg = g ^ ((r >> 1) & 3);
        *(half8*)(dst + ch * 8192 + kc * 1024 + r * 32 + sg * 8) = o;
    }
}

// ---------------- k1: NCHW gather + LayerNorm -> X[t][256] f16, k4-geometry ----------------
// R17->R18: block = (bb, h-row), thread = (w, channel-half). Every feat load is a
// 64-lane x 4B = 256B contiguous row segment (k4's measured ~6 TB/s pattern; the old
// layout fragmented each instr into 8x128B segments -> 1.4 TB/s). LN stats in-thread
// over 128 ch + one 2KB-LDS pair reduce. Pad rows (h==127 / w==127) take the uniform
// path: zero input -> xn = ln_b exactly (matches reference zero-padded LN).
__global__ __launch_bounds__(256, 2)
void k1_pack(const float* __restrict__ feat, const float* __restrict__ lnw,
             const float* __restrict__ lnb, f16* __restrict__ X) {
    __shared__ float redS[256], redQ[256];
    const int tid = threadIdx.x;
    const int w = tid & 127, cq = tid >> 7;
    const int bid = blockIdx.x;
    const int bb = bid >> 7, h = bid & 127;
    const int c0 = cq * 128;
    const bool ok = (h < 127) && (w < 127);
    const size_t bbase = (size_t)bb * (256 * 127 * 127);
    const float* p0 = feat + bbase + (size_t)c0 * 16129 + (size_t)h * 127 + w;

    half8 ov[16];                      // 128 channels as f16
    float s = 0.f, s2 = 0.f;
    if (ok) {
#pragma unroll
        for (int i = 0; i < 16; ++i) {
            half8 hv;
#pragma unroll
            for (int j = 0; j < 8; ++j) {
                float v = p0[(size_t)(i * 8 + j) * 16129];
                s += v; s2 += v * v; hv[j] = (f16)v;
            }
            ov[i] = hv;
        }
    } else {
#pragma unroll
        for (int i = 0; i < 16; ++i) {
            half8 hv;
#pragma unroll
            for (int j = 0; j < 8; ++j) hv[j] = (f16)0.f;
            ov[i] = hv;
        }
    }
    redS[tid] = s; redQ[tid] = s2;
    __syncthreads();
    float st = redS[w] + redS[w + 128];
    float qt = redQ[w] + redQ[w + 128];
    float mu = st * (1.f / 256.f);
    float rs = rsqrtf(qt * (1.f / 256.f) - mu * mu + 1e-5f);

    const int wi = h >> 2, hh = h & 3;
    const int jh = w >> 5, wl4 = (w >> 2) & 7, e = w & 3;
    const size_t t = ((size_t)((bb * 32 + wi) * 4 + jh)) * 128 + wl4 * 16 + hh * 4 + e;
    f16* xrow = X + t * 256 + c0;
#pragma unroll
    for (int i = 0; i < 16; ++i) {
        f32x4 lw0 = *(const f32x4*)(lnw + c0 + i * 8);
        f32x4 lw1 = *(const f32x4*)(lnw + c0 + i * 8 + 4);
        f32x4 lb0 = *(const f32x4*)(lnb + c0 + i * 8);
        f32x4 lb1 = *(const f32x4*)(lnb + c0 + i * 8 + 4);
        half8 o;
#pragma unroll
        for (int j = 0; j < 4; ++j) {
            o[j]     = (f16)(((float)ov[i][j]     - mu) * rs * lw0[j] + lb0[j]);
            o[j + 4] = (f16)(((float)ov[i][j + 4] - mu) * rs * lw1[j] + lb1[j]);
        }
        *(half8*)(xrow + i * 8) = o;
    }
}

// ---------------- k2: QKV GEMM  X[131072x256] @ in_w^T -> QK / VT ----------------
// Frozen at R13 best (BM=256, 8 waves, BK=32, involution staging; VGPR-bound at 2 blk/CU).
__global__ __launch_bounds__(512, 2)
void k2_qkv(const f16* __restrict__ X, const f16* __restrict__ win,
            const float* __restrict__ inb, f16* __restrict__ QK, f16* __restrict__ VT) {
    __shared__ __align__(16) char sm[49152];   // 2 bufs x (A 16K | B 8K)
    const int tid = threadIdx.x, lane = tid & 63, wv = tid >> 6;   // 8 waves
    const int nwg = gridDim.x;                 // 3072, divisible by 8
    const int bid = (blockIdx.x & 7) * (nwg >> 3) + (blockIdx.x >> 3);
    const int mt = bid / 6, nb = bid % 6;
    const size_t Mbase = (size_t)mt * 256;
    const int n0 = nb * 128;
    const int wm = wv >> 1, wn = wv & 1;       // 4 M-groups x 2 N-groups
    const int c = lane & 15, g = lane >> 4;
    const int chs = (lane & 3) ^ ((lane >> 3) & 3);   // involution source chunk

    f32x4 acc[4][4];
#pragma unroll
    for (int a = 0; a < 4; ++a)
#pragma unroll
        for (int b = 0; b < 4; ++b) acc[a][b] = f32x4{0.f, 0.f, 0.f, 0.f};

    auto stage = [&](int step, int bsel) {
        const f16* As = X + Mbase * 256 + step * 32;
        const f16* Bs = win + (size_t)n0 * 256 + step * 32;
        char* base = sm + bsel * 24576;
#pragma unroll
        for (int p = 0; p < 2; ++p) {
            int row = p * 128 + wv * 16 + (lane >> 2);
            __builtin_amdgcn_global_load_lds(
                (const __attribute__((address_space(1))) unsigned int*)(As + (size_t)row * 256 + chs * 8),
                (__attribute__((address_space(3))) unsigned int*)(base + p * 8192 + wv * 1024),
                16, 0, 0);
        }
        {
            int row = wv * 16 + (lane >> 2);
            __builtin_amdgcn_global_load_lds(
                (const __attribute__((address_space(1))) unsigned int*)(Bs + (size_t)row * 256 + chs * 8),
                (__attribute__((address_space(3))) unsigned int*)(base + 16384 + wv * 1024),
                16, 0, 0);
        }
    };
    const int rsl = (g ^ ((c >> 1) & 3)) * 16;   // swizzled 16B slot within 64B row
    auto compute = [&](int bsel) {
        char* base = sm + bsel * 24576;
        half8 a[4], b[4];
#pragma unroll
        for (int mi = 0; mi < 4; ++mi) {
            int row = wm * 64 + mi * 16 + c;
            a[mi] = *(half8*)(base + row * 64 + rsl);
        }
#pragma unroll
        for (int nt = 0; nt < 4; ++nt) {
            int row = wn * 64 + nt * 16 + c;
            b[nt] = *(half8*)(base + 16384 + row * 64 + rsl);
        }
#pragma unroll
        for (int mi = 0; mi < 4; ++mi)
#pragma unroll
            for (int nt = 0; nt < 4; ++nt)
                acc[mi][nt] = MFMA32(a[mi], b[nt], acc[mi][nt]);
    };

    stage(0, 0);
    __syncthreads();
#pragma unroll
    for (int s = 0; s < 8; ++s) {
        const int bsel = s & 1;
        if (s < 7) stage(s + 1, bsel ^ 1);
        compute(bsel);
        __syncthreads();
    }

    const f32x4 z4 = {0.f, 0.f, 0.f, 0.f};
    half4 idf;
#pragma unroll
    for (int j = 0; j < 4; ++j) idf[j] = (f16)((g * 4 + j == c) ? 1.f : 0.f);

    if (n0 < 512) {
        // Q,K: transpose via identity mfma, store row-major QK[t][512]
#pragma unroll
        for (int mi = 0; mi < 4; ++mi)
#pragma unroll
            for (int nt = 0; nt < 4; ++nt) {
                int n = n0 + wn * 64 + nt * 16 + c;
                float bias = inb[n];
                half4 h;
#pragma unroll
                for (int r = 0; r < 4; ++r) h[r] = (f16)(acc[mi][nt][r] + bias);
                f32x4 t = MFMA16(h, idf, z4);      // C/D-as-A (=T^T) times I -> transposed tile
                half4 o;
#pragma unroll
                for (int r = 0; r < 4; ++r) o[r] = (f16)t[r];
                size_t tok = Mbase + wm * 64 + mi * 16 + c;       // col of transposed tile = m
                *(half4*)(QK + tok * 512 + (n0 + wn * 64 + nt * 16 + g * 4)) = o;
            }
    } else {
        // V: store [win][d][t] directly from C/D (rows = 4 contiguous tokens)
#pragma unroll
        for (int mi = 0; mi < 4; ++mi)
#pragma unroll
            for (int nt = 0; nt < 4; ++nt) {
                int n = n0 + wn * 64 + nt * 16 + c;
                float bias = inb[n];
                half4 h;
#pragma unroll
                for (int r = 0; r < 4; ++r) h[r] = (f16)(acc[mi][nt][r] + bias);
                int d = n - 512;
                size_t tokb = Mbase + wm * 64 + mi * 16;          // window-aligned
                size_t winI = tokb >> 4;
                *(half4*)(VT + winI * 4096 + (size_t)d * 16 + g * 4) = h;
            }
    }
}

// ---------------- k3: attention + out-proj + proj + GELU -> G[t][256] f16 ----------------
// Frozen at R16 (LDS-staged, k2-geometry conflict-free image, poly-GELU, lb(256,3)).
__global__ __launch_bounds__(256, 3)
void k3_attn(const f16* __restrict__ QK, const f16* __restrict__ VT,
             const f16* __restrict__ wout, const f16* __restrict__ wproj,
             const float* __restrict__ outb, const float* __restrict__ projb,
             f16* __restrict__ G) {
    __shared__ __align__(16) char sm[32768];   // 2 x 16KB weight chunks (k2-geometry image)
    const int tid = threadIdx.x, lane = tid & 63, wv = tid >> 6;   // 4 waves
    const int c = lane & 15, g = lane >> 4;
    const size_t win = (size_t)blockIdx.x * 4 + wv;
    const f16* qrow = QK + (win * 16 + c) * 512;
    const f32x4 z4 = {0.f, 0.f, 0.f, 0.f};

    auto stageW = [&](const f16* img, int rc, int bsel) {
#pragma unroll
        for (int q2 = 0; q2 < 4; ++q2) {
            int ia = wv * 4 + q2;
            __builtin_amdgcn_global_load_lds(
                (const __attribute__((address_space(1))) unsigned int*)(img + rc * 8192 + ia * 512 + lane * 8),
                (__attribute__((address_space(3))) unsigned int*)(sm + bsel * 16384 + ia * 1024),
                16, 0, 0);
        }
    };

    stageW(wout, 0, 0);   // chunk 0 in flight under attention

    // ---- attention, all in registers; pack PV outputs as MFMA32 B-frags ofp[hq][t] ----
    half8 ofp[4][2];
#pragma unroll
    for (int hq = 0; hq < 4; ++hq) {
        half8 af0 = *(const half8*)(qrow + 256 + hq * 64 + g * 8);
        half8 af1 = *(const half8*)(qrow + 256 + hq * 64 + 32 + g * 8);
        half8 bq0 = *(const half8*)(qrow + hq * 64 + g * 8);
        half8 bq1 = *(const half8*)(qrow + hq * 64 + 32 + g * 8);
        f32x4 sacc = MFMA32(af0, bq0, z4);     // S^T[k_tok][q]
        sacc = MFMA32(af1, bq1, sacc);
        float s0 = sacc[0] * 0.125f, s1 = sacc[1] * 0.125f;
        float s2 = sacc[2] * 0.125f, s3 = sacc[3] * 0.125f;
        float mx = fmaxf(fmaxf(s0, s1), fmaxf(s2, s3));
        mx = fmaxf(mx, __shfl_xor(mx, 16));
        mx = fmaxf(mx, __shfl_xor(mx, 32));
        float p0 = __expf(s0 - mx), p1 = __expf(s1 - mx);
        float p2 = __expf(s2 - mx), p3 = __expf(s3 - mx);
        float sum = p0 + p1 + p2 + p3;
        sum += __shfl_xor(sum, 16);
        sum += __shfl_xor(sum, 32);
        float inv = 1.f / sum;
        half4 pf;
        pf[0] = (f16)(p0 * inv); pf[1] = (f16)(p1 * inv);
        pf[2] = (f16)(p2 * inv); pf[3] = (f16)(p3 * inv);
#pragma unroll
        for (int nt = 0; nt < 4; ++nt) {
            half4 vf = *(const half4*)(VT + win * 4096 + (size_t)(hq * 64 + nt * 16 + c) * 16 + g * 4);
            f32x4 o = MFMA16(vf, pf, z4);      // O^T[d][q]
#pragma unroll
            for (int r = 0; r < 4; ++r) ofp[hq][nt >> 1][(nt & 1) * 4 + r] = (f16)o[r];
        }
    }

    const int rsl = (g ^ ((c >> 1) & 3)) * 16;   // intra-row rotated 16B slot (k2 pattern)
    half8 obp[8];
    __syncthreads();

    // ---- out-proj: per 32-row weight chunk, 8 kc of 32 via MFMA32 ----
#pragma unroll
    for (int ch = 0; ch < 8; ++ch) {
        if (ch < 7) stageW(wout, ch + 1, (ch + 1) & 1);
        else        stageW(wproj, 0, (ch + 1) & 1);
        char* base = sm + (ch & 1) * 16384;
        f32x4 a0 = z4, a1 = z4;
#pragma unroll
        for (int kc = 0; kc < 8; ++kc) {
            half8 w0 = *(half8*)(base + kc * 2048 + c * 64 + rsl);
            a0 = MFMA32(w0, ofp[kc >> 1][kc & 1], a0);
            half8 w1 = *(half8*)(base + kc * 2048 + 1024 + c * 64 + rsl);
            a1 = MFMA32(w1, ofp[kc >> 1][kc & 1], a1);
        }
        f32x4 b0 = *(const f32x4*)(outb + ch * 32 + g * 4);
        f32x4 b1 = *(const f32x4*)(outb + ch * 32 + 16 + g * 4);
#pragma unroll
        for (int r = 0; r < 4; ++r) {
            obp[ch][r]     = (f16)(a0[r] + b0[r]);
            obp[ch][4 + r] = (f16)(a1[r] + b1[r]);
        }
        __syncthreads();
    }

    // ---- proj + bias + exact-grade GELU + store G ----
#pragma unroll
    for (int pc = 0; pc < 8; ++pc) {
        if (pc < 7) stageW(wproj, pc + 1, (pc + 1) & 1);
        char* base = sm + (pc & 1) * 16384;
        f32x4 a0 = z4, a1 = z4;
#pragma unroll
        for (int kc = 0; kc < 8; ++kc) {
            half8 w0 = *(half8*)(base + kc * 2048 + c * 64 + rsl);
            a0 = MFMA32(w0, obp[kc], a0);
            half8 w1 = *(half8*)(base + kc * 2048 + 1024 + c * 64 + rsl);
            a1 = MFMA32(w1, obp[kc], a1);
        }
        f32x4 b0 = *(const f32x4*)(projb + pc * 32 + g * 4);
        f32x4 b1 = *(const f32x4*)(projb + pc * 32 + 16 + g * 4);
        half4 h0, h1;
#pragma unroll
        for (int r = 0; r < 4; ++r) {
            h0[r] = (f16)gelu_f(a0[r] + b0[r]);
            h1[r] = (f16)gelu_f(a1[r] + b1[r]);
        }
        f16* grow = G + (win * 16 + c) * 256 + pc * 32;
        *(half4*)(grow + g * 4) = h0;
        *(half4*)(grow + 16 + g * 4) = h1;
        if (pc < 7) __syncthreads();
    }
}

// ---------------- k4: residual + NCHW scatter, one block per full (bb,h) row ----------------
__global__ __launch_bounds__(256, 8)
void k4_out(const f16* __restrict__ G, const float* __restrict__ feat, float* __restrict__ outp) {
    const int tid = threadIdx.x;
    const int bid = blockIdx.x;            // bb*127 + h
    const int bb = bid / 127, h = bid % 127;
    const int w = tid & 127;               // 0..127 (w==127 masked: pad column)
    const int cq = tid >> 7;               // 0..1
    const bool wok = (w < 127);
    const size_t bbase = (size_t)bb * (256 * 127 * 127);
    const int wi = h >> 2, hh = h & 3;
    const int jh = w >> 5, wl4 = (w >> 2) & 7, e = w & 3;
    const size_t t = ((size_t)((bb * 32 + wi) * 4 + jh)) * 128 + wl4 * 16 + hh * 4 + e;
    const f16* gp = G + t * 256;
    const float* fp = feat + bbase + (size_t)h * 127 + w;
    float* op = outp + bbase + (size_t)h * 127 + w;
#pragma unroll 4
    for (int ci = 0; ci < 32; ++ci) {
        const int ch = ci * 8 + cq * 4;
        if (wok) {
            half4 g4 = *(const half4*)(gp + ch);
#pragma unroll
            for (int j = 0; j < 4; ++j) {
                size_t off = (size_t)(ch + j) * 16129;
                op[off] = fp[off] + (float)g4[j];
            }
        }
    }
}

extern "C" void kernel_launch(void* const* d_in, const int* in_sizes, int n_in,
                              void* d_out, int out_size, void* d_ws, size_t ws_size,
                              hipStream_t stream) {
    const float* feat   = (const float*)d_in[0];
    const float* ln_w   = (const float*)d_in[1];
    const float* ln_b   = (const float*)d_in[2];
    const float* in_w   = (const float*)d_in[3];
    const float* in_b   = (const float*)d_in[4];
    const float* out_w  = (const float*)d_in[5];
    const float* out_b  = (const float*)d_in[6];
    const float* proj_w = (const float*)d_in[7];
    const float* proj_b = (const float*)d_in[8];

    f16* W  = (f16*)d_ws;
    f16* Xb  = W + X0;
    f16* QKb = W + QK0;
    f16* VTb = W + VT0;
    f16* Gb  = Xb;   // reuse X region for G (X dead after k2)

    k0_cast<<<768, 256, 0, stream>>>(in_w, out_w, proj_w, W);
    k1_pack<<<1024, 256, 0, stream>>>(feat, ln_w, ln_b, Xb);
    k2_qkv<<<3072, 512, 0, stream>>>(Xb, W + W_IN0, in_b, QKb, VTb);
    k3_attn<<<2048, 256, 0, stream>>>(QKb, VTb, W + W_OUT0, W + W_PROJ0, out_b, proj_b, Gb);
    k4_out<<<1016, 256, 0, stream>>>(Gb, feat, (float*)d_out);
}

// Round 19
// 337.020 us; speedup vs baseline: 1.0900x; 1.0096x over previous
//
#include <hip/hip_runtime.h>

typedef _Float16 f16;
typedef __attribute__((ext_vector_type(4))) _Float16 half4;
typedef __attribute__((ext_vector_type(8))) _Float16 half8;
typedef __attribute__((ext_vector_type(4))) float f32x4;
typedef unsigned short u16;

#define MFMA32(a,b,c) __builtin_amdgcn_mfma_f32_16x16x32_f16(a,b,c,0,0,0)
#define MFMA16(a,b,c) __builtin_amdgcn_mfma_f32_16x16x16f16(a,b,c,0,0,0)

// ws layout (f16 element offsets)
#define W_IN0   0
#define W_OUT0  196608
#define W_PROJ0 262144
#define X0      327680
#define QK0     33882112ull
#define VT0     100990976ull

// exact-grade GELU: erf via A&S 7.1.26 (|eps|<=1.5e-7)
__device__ __forceinline__ float gelu_f(float x) {
    float z = x * 0.70710678118f;
    float az = fabsf(z);
    float t = 1.f / (1.f + 0.3275911f * az);
    float e = __expf(-z * z);
    float poly = ((((1.061405429f * t - 1.453152027f) * t + 1.421413741f) * t
                   - 0.284496736f) * t + 0.254829592f) * t;
    float er = 1.f - poly * e;
    er = copysignf(er, z);
    return 0.5f * x * (1.f + er);
}

// ---------------- k0: cast weights to f16; build k2-geometry images for w_out/w_proj ----
__global__ void k0_cast(const float* __restrict__ iw, const float* __restrict__ ow,
                        const float* __restrict__ pw, f16* __restrict__ W) {
    int i = blockIdx.x * 256 + threadIdx.x;
    if (i < 196608) W[W_IN0 + i] = (f16)iw[i];
    if (i < 16384) {
        const int s = i & 8191;
        const float* src = (i < 8192) ? ow : pw;
        f16* dst = W + ((i < 8192) ? W_OUT0 : W_PROJ0);
        const int g  = s & 3;
        const int r  = (s >> 2) & 31;
        const int kc = (s >> 7) & 7;
        const int ch = s >> 10;
        const int R = ch * 32 + r;
        const int c0 = kc * 32 + g * 4;
        f32x4 v0 = *(const f32x4*)(src + R * 256 + c0);
        f32x4 v1 = *(const f32x4*)(src + R * 256 + c0 + 16);
        half8 o;
#pragma unroll
        for (int j = 0; j < 4; ++j) { o[j] = (f16)v0[j]; o[j + 4] = (f16)v1[j]; }
        const int sg = g ^ ((r >> 1) & 3);
        *(half8*)(dst + ch * 8192 + kc * 1024 + r * 32 + sg * 8) = o;
    }
}

// ---------------- k1: NCHW gather + LayerNorm -> X[t][256] f16, k4-geometry ----------------
__global__ __launch_bounds__(256, 2)
void k1_pack(const float* __restrict__ feat, const float* __restrict__ lnw,
             const float* __restrict__ lnb, f16* __restrict__ X) {
    __shared__ float redS[256], redQ[256];
    const int tid = threadIdx.x;
    const int w = tid & 127, cq = tid >> 7;
    const int bid = blockIdx.x;
    const int bb = bid >> 7, h = bid & 127;
    const int c0 = cq * 128;
    const bool ok = (h < 127) && (w < 127);
    const size_t bbase = (size_t)bb * (256 * 127 * 127);
    const float* p0 = feat + bbase + (size_t)c0 * 16129 + (size_t)h * 127 + w;

    half8 ov[16];                      // 128 channels as f16
    float s = 0.f, s2 = 0.f;
    if (ok) {
#pragma unroll
        for (int i = 0; i < 16; ++i) {
            half8 hv;
#pragma unroll
            for (int j = 0; j < 8; ++j) {
                float v = p0[(size_t)(i * 8 + j) * 16129];
                s += v; s2 += v * v; hv[j] = (f16)v;
            }
            ov[i] = hv;
        }
    } else {
#pragma unroll
        for (int i = 0; i < 16; ++i) {
            half8 hv;
#pragma unroll
            for (int j = 0; j < 8; ++j) hv[j] = (f16)0.f;
            ov[i] = hv;
        }
    }
    redS[tid] = s; redQ[tid] = s2;
    __syncthreads();
    float st = redS[w] + redS[w + 128];
    float qt = redQ[w] + redQ[w + 128];
    float mu = st * (1.f / 256.f);
    float rs = rsqrtf(qt * (1.f / 256.f) - mu * mu + 1e-5f);

    const int wi = h >> 2, hh = h & 3;
    const int jh = w >> 5, wl4 = (w >> 2) & 7, e = w & 3;
    const size_t t = ((size_t)((bb * 32 + wi) * 4 + jh)) * 128 + wl4 * 16 + hh * 4 + e;
    f16* xrow = X + t * 256 + c0;
#pragma unroll
    for (int i = 0; i < 16; ++i) {
        f32x4 lw0 = *(const f32x4*)(lnw + c0 + i * 8);
        f32x4 lw1 = *(const f32x4*)(lnw + c0 + i * 8 + 4);
        f32x4 lb0 = *(const f32x4*)(lnb + c0 + i * 8);
        f32x4 lb1 = *(const f32x4*)(lnb + c0 + i * 8 + 4);
        half8 o;
#pragma unroll
        for (int j = 0; j < 4; ++j) {
            o[j]     = (f16)(((float)ov[i][j]     - mu) * rs * lw0[j] + lb0[j]);
            o[j + 4] = (f16)(((float)ov[i][j + 4] - mu) * rs * lw1[j] + lb1[j]);
        }
        *(half8*)(xrow + i * 8) = o;
    }
}

// ---------------- k2: QKV GEMM  X[131072x256] @ in_w^T -> QK / VT ----------------
// Frozen at R13 best (BM=256, 8 waves, BK=32, involution staging; VGPR-bound at 2 blk/CU).
__global__ __launch_bounds__(512, 2)
void k2_qkv(const f16* __restrict__ X, const f16* __restrict__ win,
            const float* __restrict__ inb, f16* __restrict__ QK, f16* __restrict__ VT) {
    __shared__ __align__(16) char sm[49152];   // 2 bufs x (A 16K | B 8K)
    const int tid = threadIdx.x, lane = tid & 63, wv = tid >> 6;   // 8 waves
    const int nwg = gridDim.x;                 // 3072, divisible by 8
    const int bid = (blockIdx.x & 7) * (nwg >> 3) + (blockIdx.x >> 3);
    const int mt = bid / 6, nb = bid % 6;
    const size_t Mbase = (size_t)mt * 256;
    const int n0 = nb * 128;
    const int wm = wv >> 1, wn = wv & 1;       // 4 M-groups x 2 N-groups
    const int c = lane & 15, g = lane >> 4;
    const int chs = (lane & 3) ^ ((lane >> 3) & 3);   // involution source chunk

    f32x4 acc[4][4];
#pragma unroll
    for (int a = 0; a < 4; ++a)
#pragma unroll
        for (int b = 0; b < 4; ++b) acc[a][b] = f32x4{0.f, 0.f, 0.f, 0.f};

    auto stage = [&](int step, int bsel) {
        const f16* As = X + Mbase * 256 + step * 32;
        const f16* Bs = win + (size_t)n0 * 256 + step * 32;
        char* base = sm + bsel * 24576;
#pragma unroll
        for (int p = 0; p < 2; ++p) {
            int row = p * 128 + wv * 16 + (lane >> 2);
            __builtin_amdgcn_global_load_lds(
                (const __attribute__((address_space(1))) unsigned int*)(As + (size_t)row * 256 + chs * 8),
                (__attribute__((address_space(3))) unsigned int*)(base + p * 8192 + wv * 1024),
                16, 0, 0);
        }
        {
            int row = wv * 16 + (lane >> 2);
            __builtin_amdgcn_global_load_lds(
                (const __attribute__((address_space(1))) unsigned int*)(Bs + (size_t)row * 256 + chs * 8),
                (__attribute__((address_space(3))) unsigned int*)(base + 16384 + wv * 1024),
                16, 0, 0);
        }
    };
    const int rsl = (g ^ ((c >> 1) & 3)) * 16;   // swizzled 16B slot within 64B row
    auto compute = [&](int bsel) {
        char* base = sm + bsel * 24576;
        half8 a[4], b[4];
#pragma unroll
        for (int mi = 0; mi < 4; ++mi) {
            int row = wm * 64 + mi * 16 + c;
            a[mi] = *(half8*)(base + row * 64 + rsl);
        }
#pragma unroll
        for (int nt = 0; nt < 4; ++nt) {
            int row = wn * 64 + nt * 16 + c;
            b[nt] = *(half8*)(base + 16384 + row * 64 + rsl);
        }
#pragma unroll
        for (int mi = 0; mi < 4; ++mi)
#pragma unroll
            for (int nt = 0; nt < 4; ++nt)
                acc[mi][nt] = MFMA32(a[mi], b[nt], acc[mi][nt]);
    };

    stage(0, 0);
    __syncthreads();
#pragma unroll
    for (int s = 0; s < 8; ++s) {
        const int bsel = s & 1;
        if (s < 7) stage(s + 1, bsel ^ 1);
        compute(bsel);
        __syncthreads();
    }

    const f32x4 z4 = {0.f, 0.f, 0.f, 0.f};
    half4 idf;
#pragma unroll
    for (int j = 0; j < 4; ++j) idf[j] = (f16)((g * 4 + j == c) ? 1.f : 0.f);

    if (n0 < 512) {
        // Q,K: transpose via identity mfma, store row-major QK[t][512]
#pragma unroll
        for (int mi = 0; mi < 4; ++mi)
#pragma unroll
            for (int nt = 0; nt < 4; ++nt) {
                int n = n0 + wn * 64 + nt * 16 + c;
                float bias = inb[n];
                half4 h;
#pragma unroll
                for (int r = 0; r < 4; ++r) h[r] = (f16)(acc[mi][nt][r] + bias);
                f32x4 t = MFMA16(h, idf, z4);      // C/D-as-A (=T^T) times I -> transposed tile
                half4 o;
#pragma unroll
                for (int r = 0; r < 4; ++r) o[r] = (f16)t[r];
                size_t tok = Mbase + wm * 64 + mi * 16 + c;       // col of transposed tile = m
                *(half4*)(QK + tok * 512 + (n0 + wn * 64 + nt * 16 + g * 4)) = o;
            }
    } else {
        // V: store [win][d][t] directly from C/D (rows = 4 contiguous tokens)
#pragma unroll
        for (int mi = 0; mi < 4; ++mi)
#pragma unroll
            for (int nt = 0; nt < 4; ++nt) {
                int n = n0 + wn * 64 + nt * 16 + c;
                float bias = inb[n];
                half4 h;
#pragma unroll
                for (int r = 0; r < 4; ++r) h[r] = (f16)(acc[mi][nt][r] + bias);
                int d = n - 512;
                size_t tokb = Mbase + wm * 64 + mi * 16;          // window-aligned
                size_t winI = tokb >> 4;
                *(half4*)(VT + winI * 4096 + (size_t)d * 16 + g * 4) = h;
            }
    }
}

// ---------------- k3: attention + out-proj + proj + GELU -> G[t][256] f16 ----------------
// R18->R19: 2 windows per wave (grid 1024, still 4-wave blocks -- R14's regression was
// the 8-wave barrier group, not work-per-wave). Each weight ds_read now feeds TWO MFMAs;
// stage-drain events and weight L2 traffic halve. lb(256,2): budget 256 >> peak ~170
// (R4/R5 rule: never cap below natural usage).
__global__ __launch_bounds__(256, 2)
void k3_attn(const f16* __restrict__ QK, const f16* __restrict__ VT,
             const f16* __restrict__ wout, const f16* __restrict__ wproj,
             const float* __restrict__ outb, const float* __restrict__ projb,
             f16* __restrict__ G) {
    __shared__ __align__(16) char sm[32768];   // 2 x 16KB weight chunks (k2-geometry image)
    const int tid = threadIdx.x, lane = tid & 63, wv = tid >> 6;   // 4 waves
    const int c = lane & 15, g = lane >> 4;
    const size_t winA = (size_t)blockIdx.x * 8 + wv * 2;
    const size_t winB = winA + 1;
    const f16* qrowA = QK + (winA * 16 + c) * 512;
    const f16* qrowB = QK + (winB * 16 + c) * 512;
    const f32x4 z4 = {0.f, 0.f, 0.f, 0.f};

    auto stageW = [&](const f16* img, int rc, int bsel) {
#pragma unroll
        for (int q2 = 0; q2 < 4; ++q2) {
            int ia = wv * 4 + q2;
            __builtin_amdgcn_global_load_lds(
                (const __attribute__((address_space(1))) unsigned int*)(img + rc * 8192 + ia * 512 + lane * 8),
                (__attribute__((address_space(3))) unsigned int*)(sm + bsel * 16384 + ia * 1024),
                16, 0, 0);
        }
    };

    stageW(wout, 0, 0);   // chunk 0 in flight under attention

    // ---- attention for both windows; pack PV outputs as MFMA32 B-frags ----
    half8 ofpA[4][2], ofpB[4][2];
#pragma unroll
    for (int wsel = 0; wsel < 2; ++wsel) {
        const f16* qrow = wsel ? qrowB : qrowA;
        const size_t wn_ = wsel ? winB : winA;
#pragma unroll
        for (int hq = 0; hq < 4; ++hq) {
            half8 af0 = *(const half8*)(qrow + 256 + hq * 64 + g * 8);
            half8 af1 = *(const half8*)(qrow + 256 + hq * 64 + 32 + g * 8);
            half8 bq0 = *(const half8*)(qrow + hq * 64 + g * 8);
            half8 bq1 = *(const half8*)(qrow + hq * 64 + 32 + g * 8);
            f32x4 sacc = MFMA32(af0, bq0, z4);     // S^T[k_tok][q]
            sacc = MFMA32(af1, bq1, sacc);
            float s0 = sacc[0] * 0.125f, s1 = sacc[1] * 0.125f;
            float s2 = sacc[2] * 0.125f, s3 = sacc[3] * 0.125f;
            float mx = fmaxf(fmaxf(s0, s1), fmaxf(s2, s3));
            mx = fmaxf(mx, __shfl_xor(mx, 16));
            mx = fmaxf(mx, __shfl_xor(mx, 32));
            float p0 = __expf(s0 - mx), p1 = __expf(s1 - mx);
            float p2 = __expf(s2 - mx), p3 = __expf(s3 - mx);
            float sum = p0 + p1 + p2 + p3;
            sum += __shfl_xor(sum, 16);
            sum += __shfl_xor(sum, 32);
            float inv = 1.f / sum;
            half4 pf;
            pf[0] = (f16)(p0 * inv); pf[1] = (f16)(p1 * inv);
            pf[2] = (f16)(p2 * inv); pf[3] = (f16)(p3 * inv);
#pragma unroll
            for (int nt = 0; nt < 4; ++nt) {
                half4 vf = *(const half4*)(VT + wn_ * 4096 + (size_t)(hq * 64 + nt * 16 + c) * 16 + g * 4);
                f32x4 o = MFMA16(vf, pf, z4);      // O^T[d][q]
#pragma unroll
                for (int r = 0; r < 4; ++r) {
                    if (wsel) ofpB[hq][nt >> 1][(nt & 1) * 4 + r] = (f16)o[r];
                    else      ofpA[hq][nt >> 1][(nt & 1) * 4 + r] = (f16)o[r];
                }
            }
        }
    }

    const int rsl = (g ^ ((c >> 1) & 3)) * 16;   // intra-row rotated 16B slot (k2 pattern)
    half8 obpA[8], obpB[8];
    __syncthreads();

    // ---- out-proj: per 32-row weight chunk, 8 kc; each weight frag feeds both windows ----
#pragma unroll
    for (int ch = 0; ch < 8; ++ch) {
        if (ch < 7) stageW(wout, ch + 1, (ch + 1) & 1);
        else        stageW(wproj, 0, (ch + 1) & 1);
        char* base = sm + (ch & 1) * 16384;
        f32x4 aA0 = z4, aA1 = z4, aB0 = z4, aB1 = z4;
#pragma unroll
        for (int kc = 0; kc < 8; ++kc) {
            half8 w0 = *(half8*)(base + kc * 2048 + c * 64 + rsl);
            aA0 = MFMA32(w0, ofpA[kc >> 1][kc & 1], aA0);
            aB0 = MFMA32(w0, ofpB[kc >> 1][kc & 1], aB0);
            half8 w1 = *(half8*)(base + kc * 2048 + 1024 + c * 64 + rsl);
            aA1 = MFMA32(w1, ofpA[kc >> 1][kc & 1], aA1);
            aB1 = MFMA32(w1, ofpB[kc >> 1][kc & 1], aB1);
        }
        f32x4 b0 = *(const f32x4*)(outb + ch * 32 + g * 4);
        f32x4 b1 = *(const f32x4*)(outb + ch * 32 + 16 + g * 4);
#pragma unroll
        for (int r = 0; r < 4; ++r) {
            obpA[ch][r]     = (f16)(aA0[r] + b0[r]);
            obpA[ch][4 + r] = (f16)(aA1[r] + b1[r]);
            obpB[ch][r]     = (f16)(aB0[r] + b0[r]);
            obpB[ch][4 + r] = (f16)(aB1[r] + b1[r]);
        }
        __syncthreads();
    }

    // ---- proj + bias + exact-grade GELU + store G (both windows) ----
#pragma unroll
    for (int pc = 0; pc < 8; ++pc) {
        if (pc < 7) stageW(wproj, pc + 1, (pc + 1) & 1);
        char* base = sm + (pc & 1) * 16384;
        f32x4 aA0 = z4, aA1 = z4, aB0 = z4, aB1 = z4;
#pragma unroll
        for (int kc = 0; kc < 8; ++kc) {
            half8 w0 = *(half8*)(base + kc * 2048 + c * 64 + rsl);
            aA0 = MFMA32(w0, obpA[kc], aA0);
            aB0 = MFMA32(w0, obpB[kc], aB0);
            half8 w1 = *(half8*)(base + kc * 2048 + 1024 + c * 64 + rsl);
            aA1 = MFMA32(w1, obpA[kc], aA1);
            aB1 = MFMA32(w1, obpB[kc], aB1);
        }
        f32x4 b0 = *(const f32x4*)(projb + pc * 32 + g * 4);
        f32x4 b1 = *(const f32x4*)(projb + pc * 32 + 16 + g * 4);
        half4 hA0, hA1, hB0, hB1;
#pragma unroll
        for (int r = 0; r < 4; ++r) {
            hA0[r] = (f16)gelu_f(aA0[r] + b0[r]);
            hA1[r] = (f16)gelu_f(aA1[r] + b1[r]);
            hB0[r] = (f16)gelu_f(aB0[r] + b0[r]);
            hB1[r] = (f16)gelu_f(aB1[r] + b1[r]);
        }
        f16* growA = G + (winA * 16 + c) * 256 + pc * 32;
        *(half4*)(growA + g * 4) = hA0;
        *(half4*)(growA + 16 + g * 4) = hA1;
        f16* growB = G + (winB * 16 + c) * 256 + pc * 32;
        *(half4*)(growB + g * 4) = hB0;
        *(half4*)(growB + 16 + g * 4) = hB1;
        if (pc < 7) __syncthreads();
    }
}

// ---------------- k4: residual + NCHW scatter, one block per full (bb,h) row ----------------
__global__ __launch_bounds__(256, 8)
void k4_out(const f16* __restrict__ G, const float* __restrict__ feat, float* __restrict__ outp) {
    const int tid = threadIdx.x;
    const int bid = blockIdx.x;            // bb*127 + h
    const int bb = bid / 127, h = bid % 127;
    const int w = tid & 127;               // 0..127 (w==127 masked: pad column)
    const int cq = tid >> 7;               // 0..1
    const bool wok = (w < 127);
    const size_t bbase = (size_t)bb * (256 * 127 * 127);
    const int wi = h >> 2, hh = h & 3;
    const int jh = w >> 5, wl4 = (w >> 2) & 7, e = w & 3;
    const size_t t = ((size_t)((bb * 32 + wi) * 4 + jh)) * 128 + wl4 * 16 + hh * 4 + e;
    const f16* gp = G + t * 256;
    const float* fp = feat + bbase + (size_t)h * 127 + w;
    float* op = outp + bbase + (size_t)h * 127 + w;
#pragma unroll 4
    for (int ci = 0; ci < 32; ++ci) {
        const int ch = ci * 8 + cq * 4;
        if (wok) {
            half4 g4 = *(const half4*)(gp + ch);
#pragma unroll
            for (int j = 0; j < 4; ++j) {
                size_t off = (size_t)(ch + j) * 16129;
                op[off] = fp[off] + (float)g4[j];
            }
        }
    }
}

extern "C" void kernel_launch(void* const* d_in, const int* in_sizes, int n_in,
                              void* d_out, int out_size, void* d_ws, size_t ws_size,
                              hipStream_t stream) {
    const float* feat   = (const float*)d_in[0];
    const float* ln_w   = (const float*)d_in[1];
    const float* ln_b   = (const float*)d_in[2];
    const float* in_w   = (const float*)d_in[3];
    const float* in_b   = (const float*)d_in[4];
    const float* out_w  = (const float*)d_in[5];
    const float* out_b  = (const float*)d_in[6];
    const float* proj_w = (const float*)d_in[7];
    const float* proj_b = (const float*)d_in[8];

    f16* W  = (f16*)d_ws;
    f16* Xb  = W + X0;
    f16* QKb = W + QK0;
    f16* VTb = W + VT0;
    f16* Gb  = Xb;   // reuse X region for G (X dead after k2)

    k0_cast<<<768, 256, 0, stream>>>(in_w, out_w, proj_w, W);
    k1_pack<<<1024, 256, 0, stream>>>(feat, ln_w, ln_b, Xb);
    k2_qkv<<<3072, 512, 0, stream>>>(Xb, W + W_IN0, in_b, QKb, VTb);
    k3_attn<<<1024, 256, 0, stream>>>(QKb, VTb, W + W_OUT0, W + W_PROJ0, out_b, proj_b, Gb);
    k4_out<<<1016, 256, 0, stream>>>(Gb, feat, (float*)d_out);
}

// Round 20
// 336.917 us; speedup vs baseline: 1.0903x; 1.0003x over previous
//
#include <hip/hip_runtime.h>

typedef _Float16 f16;
typedef __attribute__((ext_vector_type(4))) _Float16 half4;
typedef __attribute__((ext_vector_type(8))) _Float16 half8;
typedef __attribute__((ext_vector_type(4))) float f32x4;
typedef unsigned short u16;

#define MFMA32(a,b,c) __builtin_amdgcn_mfma_f32_16x16x32_f16(a,b,c,0,0,0)
#define MFMA16(a,b,c) __builtin_amdgcn_mfma_f32_16x16x16f16(a,b,c,0,0,0)

// ws layout (f16 element offsets)
#define W_IN0   0
#define W_OUT0  196608
#define W_PROJ0 262144
#define X0      327680
#define QK0     33882112ull
#define VT0     100990976ull

// exact-grade GELU: erf via A&S 7.1.26 (|eps|<=1.5e-7)
__device__ __forceinline__ float gelu_f(float x) {
    float z = x * 0.70710678118f;
    float az = fabsf(z);
    float t = 1.f / (1.f + 0.3275911f * az);
    float e = __expf(-z * z);
    float poly = ((((1.061405429f * t - 1.453152027f) * t + 1.421413741f) * t
                   - 0.284496736f) * t + 0.254829592f) * t;
    float er = 1.f - poly * e;
    er = copysignf(er, z);
    return 0.5f * x * (1.f + er);
}

// ---------------- k0: cast weights to f16; build k2-geometry images for w_out/w_proj ----
__global__ void k0_cast(const float* __restrict__ iw, const float* __restrict__ ow,
                        const float* __restrict__ pw, f16* __restrict__ W) {
    int i = blockIdx.x * 256 + threadIdx.x;
    if (i < 196608) W[W_IN0 + i] = (f16)iw[i];
    if (i < 16384) {
        const int s = i & 8191;
        const float* src = (i < 8192) ? ow : pw;
        f16* dst = W + ((i < 8192) ? W_OUT0 : W_PROJ0);
        const int g  = s & 3;
        const int r  = (s >> 2) & 31;
        const int kc = (s >> 7) & 7;
        const int ch = s >> 10;
        const int R = ch * 32 + r;
        const int c0 = kc * 32 + g * 4;
        f32x4 v0 = *(const f32x4*)(src + R * 256 + c0);
        f32x4 v1 = *(const f32x4*)(src + R * 256 + c0 + 16);
        half8 o;
#pragma unroll
        for (int j = 0; j < 4; ++j) { o[j] = (f16)v0[j]; o[j + 4] = (f16)v1[j]; }
        const int sg = g ^ ((r >> 1) & 3);
        *(half8*)(dst + ch * 8192 + kc * 1024 + r * 32 + sg * 8) = o;
    }
}

// ---------------- k1: NCHW gather + LayerNorm -> X[t][256] f16, k4-geometry ----------------
__global__ __launch_bounds__(256, 2)
void k1_pack(const float* __restrict__ feat, const float* __restrict__ lnw,
             const float* __restrict__ lnb, f16* __restrict__ X) {
    __shared__ float redS[256], redQ[256];
    const int tid = threadIdx.x;
    const int w = tid & 127, cq = tid >> 7;
    const int bid = blockIdx.x;
    const int bb = bid >> 7, h = bid & 127;
    const int c0 = cq * 128;
    const bool ok = (h < 127) && (w < 127);
    const size_t bbase = (size_t)bb * (256 * 127 * 127);
    const float* p0 = feat + bbase + (size_t)c0 * 16129 + (size_t)h * 127 + w;

    half8 ov[16];                      // 128 channels as f16
    float s = 0.f, s2 = 0.f;
    if (ok) {
#pragma unroll
        for (int i = 0; i < 16; ++i) {
            half8 hv;
#pragma unroll
            for (int j = 0; j < 8; ++j) {
                float v = p0[(size_t)(i * 8 + j) * 16129];
                s += v; s2 += v * v; hv[j] = (f16)v;
            }
            ov[i] = hv;
        }
    } else {
#pragma unroll
        for (int i = 0; i < 16; ++i) {
            half8 hv;
#pragma unroll
            for (int j = 0; j < 8; ++j) hv[j] = (f16)0.f;
            ov[i] = hv;
        }
    }
    redS[tid] = s; redQ[tid] = s2;
    __syncthreads();
    float st = redS[w] + redS[w + 128];
    float qt = redQ[w] + redQ[w + 128];
    float mu = st * (1.f / 256.f);
    float rs = rsqrtf(qt * (1.f / 256.f) - mu * mu + 1e-5f);

    const int wi = h >> 2, hh = h & 3;
    const int jh = w >> 5, wl4 = (w >> 2) & 7, e = w & 3;
    const size_t t = ((size_t)((bb * 32 + wi) * 4 + jh)) * 128 + wl4 * 16 + hh * 4 + e;
    f16* xrow = X + t * 256 + c0;
#pragma unroll
    for (int i = 0; i < 16; ++i) {
        f32x4 lw0 = *(const f32x4*)(lnw + c0 + i * 8);
        f32x4 lw1 = *(const f32x4*)(lnw + c0 + i * 8 + 4);
        f32x4 lb0 = *(const f32x4*)(lnb + c0 + i * 8);
        f32x4 lb1 = *(const f32x4*)(lnb + c0 + i * 8 + 4);
        half8 o;
#pragma unroll
        for (int j = 0; j < 4; ++j) {
            o[j]     = (f16)(((float)ov[i][j]     - mu) * rs * lw0[j] + lb0[j]);
            o[j + 4] = (f16)(((float)ov[i][j + 4] - mu) * rs * lw1[j] + lb1[j]);
        }
        *(half8*)(xrow + i * 8) = o;
    }
}

// ---------------- k2: QKV GEMM  X[131072x256] @ in_w^T -> QK / VT ----------------
// R19->R20: T4 counted-vmcnt pipeline, triple-buffered stage (3 x 24KB LDS).
// Per step: vmcnt(3) waits ONLY stage(s) (issued 2 iters ago, ~2 compute phases of
// slack); stage(s+1) stays in flight ACROSS the raw s_barrier (never drained to 0 in
// the loop -- the AITER/m218 pattern). stage(s+2) issued AFTER the barrier so it can't
// race another wave's compute(s-1) on buffer (s+2)%3. Tail step uses vmcnt(0).
__global__ __launch_bounds__(512, 2)
void k2_qkv(const f16* __restrict__ X, const f16* __restrict__ win,
            const float* __restrict__ inb, f16* __restrict__ QK, f16* __restrict__ VT) {
    __shared__ __align__(16) char sm[73728];   // 3 bufs x (A 16K | B 8K)
    const int tid = threadIdx.x, lane = tid & 63, wv = tid >> 6;   // 8 waves
    const int nwg = gridDim.x;                 // 3072, divisible by 8
    const int bid = (blockIdx.x & 7) * (nwg >> 3) + (blockIdx.x >> 3);
    const int mt = bid / 6, nb = bid % 6;
    const size_t Mbase = (size_t)mt * 256;
    const int n0 = nb * 128;
    const int wm = wv >> 1, wn = wv & 1;       // 4 M-groups x 2 N-groups
    const int c = lane & 15, g = lane >> 4;
    const int chs = (lane & 3) ^ ((lane >> 3) & 3);   // involution source chunk

    f32x4 acc[4][4];
#pragma unroll
    for (int a = 0; a < 4; ++a)
#pragma unroll
        for (int b = 0; b < 4; ++b) acc[a][b] = f32x4{0.f, 0.f, 0.f, 0.f};

    auto stage = [&](int step, int bsel) {
        const f16* As = X + Mbase * 256 + step * 32;
        const f16* Bs = win + (size_t)n0 * 256 + step * 32;
        char* base = sm + bsel * 24576;
#pragma unroll
        for (int p = 0; p < 2; ++p) {
            int row = p * 128 + wv * 16 + (lane >> 2);
            __builtin_amdgcn_global_load_lds(
                (const __attribute__((address_space(1))) unsigned int*)(As + (size_t)row * 256 + chs * 8),
                (__attribute__((address_space(3))) unsigned int*)(base + p * 8192 + wv * 1024),
                16, 0, 0);
        }
        {
            int row = wv * 16 + (lane >> 2);
            __builtin_amdgcn_global_load_lds(
                (const __attribute__((address_space(1))) unsigned int*)(Bs + (size_t)row * 256 + chs * 8),
                (__attribute__((address_space(3))) unsigned int*)(base + 16384 + wv * 1024),
                16, 0, 0);
        }
    };
    const int rsl = (g ^ ((c >> 1) & 3)) * 16;   // swizzled 16B slot within 64B row
    auto compute = [&](int bsel) {
        char* base = sm + bsel * 24576;
        half8 a[4], b[4];
#pragma unroll
        for (int mi = 0; mi < 4; ++mi) {
            int row = wm * 64 + mi * 16 + c;
            a[mi] = *(half8*)(base + row * 64 + rsl);
        }
#pragma unroll
        for (int nt = 0; nt < 4; ++nt) {
            int row = wn * 64 + nt * 16 + c;
            b[nt] = *(half8*)(base + 16384 + row * 64 + rsl);
        }
#pragma unroll
        for (int mi = 0; mi < 4; ++mi)
#pragma unroll
            for (int nt = 0; nt < 4; ++nt)
                acc[mi][nt] = MFMA32(a[mi], b[nt], acc[mi][nt]);
    };

    stage(0, 0);
    stage(1, 1);
#pragma unroll
    for (int s = 0; s < 8; ++s) {
        if (s == 7) asm volatile("s_waitcnt vmcnt(0)" ::: "memory");
        else        asm volatile("s_waitcnt vmcnt(3)" ::: "memory");
        __builtin_amdgcn_s_barrier();
        if (s < 6) stage(s + 2, (s + 2) % 3);
        compute(s % 3);
    }

    const f32x4 z4 = {0.f, 0.f, 0.f, 0.f};
    half4 idf;
#pragma unroll
    for (int j = 0; j < 4; ++j) idf[j] = (f16)((g * 4 + j == c) ? 1.f : 0.f);

    if (n0 < 512) {
        // Q,K: transpose via identity mfma, store row-major QK[t][512]
#pragma unroll
        for (int mi = 0; mi < 4; ++mi)
#pragma unroll
            for (int nt = 0; nt < 4; ++nt) {
                int n = n0 + wn * 64 + nt * 16 + c;
                float bias = inb[n];
                half4 h;
#pragma unroll
                for (int r = 0; r < 4; ++r) h[r] = (f16)(acc[mi][nt][r] + bias);
                f32x4 t = MFMA16(h, idf, z4);      // C/D-as-A (=T^T) times I -> transposed tile
                half4 o;
#pragma unroll
                for (int r = 0; r < 4; ++r) o[r] = (f16)t[r];
                size_t tok = Mbase + wm * 64 + mi * 16 + c;       // col of transposed tile = m
                *(half4*)(QK + tok * 512 + (n0 + wn * 64 + nt * 16 + g * 4)) = o;
            }
    } else {
        // V: store [win][d][t] directly from C/D (rows = 4 contiguous tokens)
#pragma unroll
        for (int mi = 0; mi < 4; ++mi)
#pragma unroll
            for (int nt = 0; nt < 4; ++nt) {
                int n = n0 + wn * 64 + nt * 16 + c;
                float bias = inb[n];
                half4 h;
#pragma unroll
                for (int r = 0; r < 4; ++r) h[r] = (f16)(acc[mi][nt][r] + bias);
                int d = n - 512;
                size_t tokb = Mbase + wm * 64 + mi * 16;          // window-aligned
                size_t winI = tokb >> 4;
                *(half4*)(VT + winI * 4096 + (size_t)d * 16 + g * 4) = h;
            }
    }
}

// ---------------- k3: attention + out-proj + proj + GELU -> G[t][256] f16 ----------------
// Frozen at R19 (2 windows/wave, 4-wave blocks, k2-geometry image, poly-GELU, lb(256,2)).
__global__ __launch_bounds__(256, 2)
void k3_attn(const f16* __restrict__ QK, const f16* __restrict__ VT,
             const f16* __restrict__ wout, const f16* __restrict__ wproj,
             const float* __restrict__ outb, const float* __restrict__ projb,
             f16* __restrict__ G) {
    __shared__ __align__(16) char sm[32768];   // 2 x 16KB weight chunks (k2-geometry image)
    const int tid = threadIdx.x, lane = tid & 63, wv = tid >> 6;   // 4 waves
    const int c = lane & 15, g = lane >> 4;
    const size_t winA = (size_t)blockIdx.x * 8 + wv * 2;
    const size_t winB = winA + 1;
    const f16* qrowA = QK + (winA * 16 + c) * 512;
    const f16* qrowB = QK + (winB * 16 + c) * 512;
    const f32x4 z4 = {0.f, 0.f, 0.f, 0.f};

    auto stageW = [&](const f16* img, int rc, int bsel) {
#pragma unroll
        for (int q2 = 0; q2 < 4; ++q2) {
            int ia = wv * 4 + q2;
            __builtin_amdgcn_global_load_lds(
                (const __attribute__((address_space(1))) unsigned int*)(img + rc * 8192 + ia * 512 + lane * 8),
                (__attribute__((address_space(3))) unsigned int*)(sm + bsel * 16384 + ia * 1024),
                16, 0, 0);
        }
    };

    stageW(wout, 0, 0);   // chunk 0 in flight under attention

    // ---- attention for both windows; pack PV outputs as MFMA32 B-frags ----
    half8 ofpA[4][2], ofpB[4][2];
#pragma unroll
    for (int wsel = 0; wsel < 2; ++wsel) {
        const f16* qrow = wsel ? qrowB : qrowA;
        const size_t wn_ = wsel ? winB : winA;
#pragma unroll
        for (int hq = 0; hq < 4; ++hq) {
            half8 af0 = *(const half8*)(qrow + 256 + hq * 64 + g * 8);
            half8 af1 = *(const half8*)(qrow + 256 + hq * 64 + 32 + g * 8);
            half8 bq0 = *(const half8*)(qrow + hq * 64 + g * 8);
            half8 bq1 = *(const half8*)(qrow + hq * 64 + 32 + g * 8);
            f32x4 sacc = MFMA32(af0, bq0, z4);     // S^T[k_tok][q]
            sacc = MFMA32(af1, bq1, sacc);
            float s0 = sacc[0] * 0.125f, s1 = sacc[1] * 0.125f;
            float s2 = sacc[2] * 0.125f, s3 = sacc[3] * 0.125f;
            float mx = fmaxf(fmaxf(s0, s1), fmaxf(s2, s3));
            mx = fmaxf(mx, __shfl_xor(mx, 16));
            mx = fmaxf(mx, __shfl_xor(mx, 32));
            float p0 = __expf(s0 - mx), p1 = __expf(s1 - mx);
            float p2 = __expf(s2 - mx), p3 = __expf(s3 - mx);
            float sum = p0 + p1 + p2 + p3;
            sum += __shfl_xor(sum, 16);
            sum += __shfl_xor(sum, 32);
            float inv = 1.f / sum;
            half4 pf;
            pf[0] = (f16)(p0 * inv); pf[1] = (f16)(p1 * inv);
            pf[2] = (f16)(p2 * inv); pf[3] = (f16)(p3 * inv);
#pragma unroll
            for (int nt = 0; nt < 4; ++nt) {
                half4 vf = *(const half4*)(VT + wn_ * 4096 + (size_t)(hq * 64 + nt * 16 + c) * 16 + g * 4);
                f32x4 o = MFMA16(vf, pf, z4);      // O^T[d][q]
#pragma unroll
                for (int r = 0; r < 4; ++r) {
                    if (wsel) ofpB[hq][nt >> 1][(nt & 1) * 4 + r] = (f16)o[r];
                    else      ofpA[hq][nt >> 1][(nt & 1) * 4 + r] = (f16)o[r];
                }
            }
        }
    }

    const int rsl = (g ^ ((c >> 1) & 3)) * 16;   // intra-row rotated 16B slot (k2 pattern)
    half8 obpA[8], obpB[8];
    __syncthreads();

    // ---- out-proj: per 32-row weight chunk, 8 kc; each weight frag feeds both windows ----
#pragma unroll
    for (int ch = 0; ch < 8; ++ch) {
        if (ch < 7) stageW(wout, ch + 1, (ch + 1) & 1);
        else        stageW(wproj, 0, (ch + 1) & 1);
        char* base = sm + (ch & 1) * 16384;
        f32x4 aA0 = z4, aA1 = z4, aB0 = z4, aB1 = z4;
#pragma unroll
        for (int kc = 0; kc < 8; ++kc) {
            half8 w0 = *(half8*)(base + kc * 2048 + c * 64 + rsl);
            aA0 = MFMA32(w0, ofpA[kc >> 1][kc & 1], aA0);
            aB0 = MFMA32(w0, ofpB[kc >> 1][kc & 1], aB0);
            half8 w1 = *(half8*)(base + kc * 2048 + 1024 + c * 64 + rsl);
            aA1 = MFMA32(w1, ofpA[kc >> 1][kc & 1], aA1);
            aB1 = MFMA32(w1, ofpB[kc >> 1][kc & 1], aB1);
        }
        f32x4 b0 = *(const f32x4*)(outb + ch * 32 + g * 4);
        f32x4 b1 = *(const f32x4*)(outb + ch * 32 + 16 + g * 4);
#pragma unroll
        for (int r = 0; r < 4; ++r) {
            obpA[ch][r]     = (f16)(aA0[r] + b0[r]);
            obpA[ch][4 + r] = (f16)(aA1[r] + b1[r]);
            obpB[ch][r]     = (f16)(aB0[r] + b0[r]);
            obpB[ch][4 + r] = (f16)(aB1[r] + b1[r]);
        }
        __syncthreads();
    }

    // ---- proj + bias + exact-grade GELU + store G (both windows) ----
#pragma unroll
    for (int pc = 0; pc < 8; ++pc) {
        if (pc < 7) stageW(wproj, pc + 1, (pc + 1) & 1);
        char* base = sm + (pc & 1) * 16384;
        f32x4 aA0 = z4, aA1 = z4, aB0 = z4, aB1 = z4;
#pragma unroll
        for (int kc = 0; kc < 8; ++kc) {
            half8 w0 = *(half8*)(base + kc * 2048 + c * 64 + rsl);
            aA0 = MFMA32(w0, obpA[kc], aA0);
            aB0 = MFMA32(w0, obpB[kc], aB0);
            half8 w1 = *(half8*)(base + kc * 2048 + 1024 + c * 64 + rsl);
            aA1 = MFMA32(w1, obpA[kc], aA1);
            aB1 = MFMA32(w1, obpB[kc], aB1);
        }
        f32x4 b0 = *(const f32x4*)(projb + pc * 32 + g * 4);
        f32x4 b1 = *(const f32x4*)(projb + pc * 32 + 16 + g * 4);
        half4 hA0, hA1, hB0, hB1;
#pragma unroll
        for (int r = 0; r < 4; ++r) {
            hA0[r] = (f16)gelu_f(aA0[r] + b0[r]);
            hA1[r] = (f16)gelu_f(aA1[r] + b1[r]);
            hB0[r] = (f16)gelu_f(aB0[r] + b0[r]);
            hB1[r] = (f16)gelu_f(aB1[r] + b1[r]);
        }
        f16* growA = G + (winA * 16 + c) * 256 + pc * 32;
        *(half4*)(growA + g * 4) = hA0;
        *(half4*)(growA + 16 + g * 4) = hA1;
        f16* growB = G + (winB * 16 + c) * 256 + pc * 32;
        *(half4*)(growB + g * 4) = hB0;
        *(half4*)(growB + 16 + g * 4) = hB1;
        if (pc < 7) __syncthreads();
    }
}

// ---------------- k4: residual + NCHW scatter, one block per full (bb,h) row ----------------
__global__ __launch_bounds__(256, 8)
void k4_out(const f16* __restrict__ G, const float* __restrict__ feat, float* __restrict__ outp) {
    const int tid = threadIdx.x;
    const int bid = blockIdx.x;            // bb*127 + h
    const int bb = bid / 127, h = bid % 127;
    const int w = tid & 127;               // 0..127 (w==127 masked: pad column)
    const int cq = tid >> 7;               // 0..1
    const bool wok = (w < 127);
    const size_t bbase = (size_t)bb * (256 * 127 * 127);
    const int wi = h >> 2, hh = h & 3;
    const int jh = w >> 5, wl4 = (w >> 2) & 7, e = w & 3;
    const size_t t = ((size_t)((bb * 32 + wi) * 4 + jh)) * 128 + wl4 * 16 + hh * 4 + e;
    const f16* gp = G + t * 256;
    const float* fp = feat + bbase + (size_t)h * 127 + w;
    float* op = outp + bbase + (size_t)h * 127 + w;
#pragma unroll 4
    for (int ci = 0; ci < 32; ++ci) {
        const int ch = ci * 8 + cq * 4;
        if (wok) {
            half4 g4 = *(const half4*)(gp + ch);
#pragma unroll
            for (int j = 0; j < 4; ++j) {
                size_t off = (size_t)(ch + j) * 16129;
                op[off] = fp[off] + (float)g4[j];
            }
        }
    }
}

extern "C" void kernel_launch(void* const* d_in, const int* in_sizes, int n_in,
                              void* d_out, int out_size, void* d_ws, size_t ws_size,
                              hipStream_t stream) {
    const float* feat   = (const float*)d_in[0];
    const float* ln_w   = (const float*)d_in[1];
    const float* ln_b   = (const float*)d_in[2];
    const float* in_w   = (const float*)d_in[3];
    const float* in_b   = (const float*)d_in[4];
    const float* out_w  = (const float*)d_in[5];
    const float* out_b  = (const float*)d_in[6];
    const float* proj_w = (const float*)d_in[7];
    const float* proj_b = (const float*)d_in[8];

    f16* W  = (f16*)d_ws;
    f16* Xb  = W + X0;
    f16* QKb = W + QK0;
    f16* VTb = W + VT0;
    f16* Gb  = Xb;   // reuse X region for G (X dead after k2)

    k0_cast<<<768, 256, 0, stream>>>(in_w, out_w, proj_w, W);
    k1_pack<<<1024, 256, 0, stream>>>(feat, ln_w, ln_b, Xb);
    k2_qkv<<<3072, 512, 0, stream>>>(Xb, W + W_IN0, in_b, QKb, VTb);
    k3_attn<<<1024, 256, 0, stream>>>(QKb, VTb, W + W_OUT0, W + W_PROJ0, out_b, proj_b, Gb);
    k4_out<<<1016, 256, 0, stream>>>(Gb, feat, (float*)d_out);
}

// Round 21
// 333.413 us; speedup vs baseline: 1.1018x; 1.0105x over previous
//
#include <hip/hip_runtime.h>

typedef _Float16 f16;
typedef __attribute__((ext_vector_type(4))) _Float16 half4;
typedef __attribute__((ext_vector_type(8))) _Float16 half8;
typedef __attribute__((ext_vector_type(4))) float f32x4;
typedef unsigned short u16;

#define MFMA32(a,b,c) __builtin_amdgcn_mfma_f32_16x16x32_f16(a,b,c,0,0,0)
#define MFMA16(a,b,c) __builtin_amdgcn_mfma_f32_16x16x16f16(a,b,c,0,0,0)

// ws layout (f16 element offsets)
#define W_IN0   0
#define W_OUT0  196608
#define W_PROJ0 262144
#define X0      327680
#define QK0     33882112ull
#define VT0     100990976ull

// exact-grade GELU: erf via A&S 7.1.26 (|eps|<=1.5e-7)
__device__ __forceinline__ float gelu_f(float x) {
    float z = x * 0.70710678118f;
    float az = fabsf(z);
    float t = 1.f / (1.f + 0.3275911f * az);
    float e = __expf(-z * z);
    float poly = ((((1.061405429f * t - 1.453152027f) * t + 1.421413741f) * t
                   - 0.284496736f) * t + 0.254829592f) * t;
    float er = 1.f - poly * e;
    er = copysignf(er, z);
    return 0.5f * x * (1.f + er);
}

// ---------------- k0: cast weights to f16; build k2-geometry images for w_out/w_proj ----
__global__ void k0_cast(const float* __restrict__ iw, const float* __restrict__ ow,
                        const float* __restrict__ pw, f16* __restrict__ W) {
    int i = blockIdx.x * 256 + threadIdx.x;
    if (i < 196608) W[W_IN0 + i] = (f16)iw[i];
    if (i < 16384) {
        const int s = i & 8191;
        const float* src = (i < 8192) ? ow : pw;
        f16* dst = W + ((i < 8192) ? W_OUT0 : W_PROJ0);
        const int g  = s & 3;
        const int r  = (s >> 2) & 31;
        const int kc = (s >> 7) & 7;
        const int ch = s >> 10;
        const int R = ch * 32 + r;
        const int c0 = kc * 32 + g * 4;
        f32x4 v0 = *(const f32x4*)(src + R * 256 + c0);
        f32x4 v1 = *(const f32x4*)(src + R * 256 + c0 + 16);
        half8 o;
#pragma unroll
        for (int j = 0; j < 4; ++j) { o[j] = (f16)v0[j]; o[j + 4] = (f16)v1[j]; }
        const int sg = g ^ ((r >> 1) & 3);
        *(half8*)(dst + ch * 8192 + kc * 1024 + r * 32 + sg * 8) = o;
    }
}

// ---------------- k1: NCHW gather + LayerNorm -> X[t][256] f16, k4-geometry ----------------
__global__ __launch_bounds__(256, 2)
void k1_pack(const float* __restrict__ feat, const float* __restrict__ lnw,
             const float* __restrict__ lnb, f16* __restrict__ X) {
    __shared__ float redS[256], redQ[256];
    const int tid = threadIdx.x;
    const int w = tid & 127, cq = tid >> 7;
    const int bid = blockIdx.x;
    const int bb = bid >> 7, h = bid & 127;
    const int c0 = cq * 128;
    const bool ok = (h < 127) && (w < 127);
    const size_t bbase = (size_t)bb * (256 * 127 * 127);
    const float* p0 = feat + bbase + (size_t)c0 * 16129 + (size_t)h * 127 + w;

    half8 ov[16];                      // 128 channels as f16
    float s = 0.f, s2 = 0.f;
    if (ok) {
#pragma unroll
        for (int i = 0; i < 16; ++i) {
            half8 hv;
#pragma unroll
            for (int j = 0; j < 8; ++j) {
                float v = p0[(size_t)(i * 8 + j) * 16129];
                s += v; s2 += v * v; hv[j] = (f16)v;
            }
            ov[i] = hv;
        }
    } else {
#pragma unroll
        for (int i = 0; i < 16; ++i) {
            half8 hv;
#pragma unroll
            for (int j = 0; j < 8; ++j) hv[j] = (f16)0.f;
            ov[i] = hv;
        }
    }
    redS[tid] = s; redQ[tid] = s2;
    __syncthreads();
    float st = redS[w] + redS[w + 128];
    float qt = redQ[w] + redQ[w + 128];
    float mu = st * (1.f / 256.f);
    float rs = rsqrtf(qt * (1.f / 256.f) - mu * mu + 1e-5f);

    const int wi = h >> 2, hh = h & 3;
    const int jh = w >> 5, wl4 = (w >> 2) & 7, e = w & 3;
    const size_t t = ((size_t)((bb * 32 + wi) * 4 + jh)) * 128 + wl4 * 16 + hh * 4 + e;
    f16* xrow = X + t * 256 + c0;
#pragma unroll
    for (int i = 0; i < 16; ++i) {
        f32x4 lw0 = *(const f32x4*)(lnw + c0 + i * 8);
        f32x4 lw1 = *(const f32x4*)(lnw + c0 + i * 8 + 4);
        f32x4 lb0 = *(const f32x4*)(lnb + c0 + i * 8);
        f32x4 lb1 = *(const f32x4*)(lnb + c0 + i * 8 + 4);
        half8 o;
#pragma unroll
        for (int j = 0; j < 4; ++j) {
            o[j]     = (f16)(((float)ov[i][j]     - mu) * rs * lw0[j] + lb0[j]);
            o[j + 4] = (f16)(((float)ov[i][j + 4] - mu) * rs * lw1[j] + lb1[j]);
        }
        *(half8*)(xrow + i * 8) = o;
    }
}

// ---------------- k2: QKV GEMM  X[131072x256] @ in_w^T -> QK / VT ----------------
// R20 T4 pipeline (triple buffer, counted vmcnt, raw barrier) + R21: T5 setprio on the
// MFMA cluster (phase role-split exists -> scheduler can favor MFMA-entering waves).
__global__ __launch_bounds__(512, 2)
void k2_qkv(const f16* __restrict__ X, const f16* __restrict__ win,
            const float* __restrict__ inb, f16* __restrict__ QK, f16* __restrict__ VT) {
    __shared__ __align__(16) char sm[73728];   // 3 bufs x (A 16K | B 8K)
    const int tid = threadIdx.x, lane = tid & 63, wv = tid >> 6;   // 8 waves
    const int nwg = gridDim.x;                 // 3072, divisible by 8
    const int bid = (blockIdx.x & 7) * (nwg >> 3) + (blockIdx.x >> 3);
    const int mt = bid / 6, nb = bid % 6;
    const size_t Mbase = (size_t)mt * 256;
    const int n0 = nb * 128;
    const int wm = wv >> 1, wn = wv & 1;       // 4 M-groups x 2 N-groups
    const int c = lane & 15, g = lane >> 4;
    const int chs = (lane & 3) ^ ((lane >> 3) & 3);   // involution source chunk

    f32x4 acc[4][4];
#pragma unroll
    for (int a = 0; a < 4; ++a)
#pragma unroll
        for (int b = 0; b < 4; ++b) acc[a][b] = f32x4{0.f, 0.f, 0.f, 0.f};

    auto stage = [&](int step, int bsel) {
        const f16* As = X + Mbase * 256 + step * 32;
        const f16* Bs = win + (size_t)n0 * 256 + step * 32;
        char* base = sm + bsel * 24576;
#pragma unroll
        for (int p = 0; p < 2; ++p) {
            int row = p * 128 + wv * 16 + (lane >> 2);
            __builtin_amdgcn_global_load_lds(
                (const __attribute__((address_space(1))) unsigned int*)(As + (size_t)row * 256 + chs * 8),
                (__attribute__((address_space(3))) unsigned int*)(base + p * 8192 + wv * 1024),
                16, 0, 0);
        }
        {
            int row = wv * 16 + (lane >> 2);
            __builtin_amdgcn_global_load_lds(
                (const __attribute__((address_space(1))) unsigned int*)(Bs + (size_t)row * 256 + chs * 8),
                (__attribute__((address_space(3))) unsigned int*)(base + 16384 + wv * 1024),
                16, 0, 0);
        }
    };
    const int rsl = (g ^ ((c >> 1) & 3)) * 16;   // swizzled 16B slot within 64B row
    auto compute = [&](int bsel) {
        char* base = sm + bsel * 24576;
        half8 a[4], b[4];
#pragma unroll
        for (int mi = 0; mi < 4; ++mi) {
            int row = wm * 64 + mi * 16 + c;
            a[mi] = *(half8*)(base + row * 64 + rsl);
        }
#pragma unroll
        for (int nt = 0; nt < 4; ++nt) {
            int row = wn * 64 + nt * 16 + c;
            b[nt] = *(half8*)(base + 16384 + row * 64 + rsl);
        }
        __builtin_amdgcn_s_setprio(1);
#pragma unroll
        for (int mi = 0; mi < 4; ++mi)
#pragma unroll
            for (int nt = 0; nt < 4; ++nt)
                acc[mi][nt] = MFMA32(a[mi], b[nt], acc[mi][nt]);
        __builtin_amdgcn_s_setprio(0);
    };

    stage(0, 0);
    stage(1, 1);
#pragma unroll
    for (int s = 0; s < 8; ++s) {
        if (s == 7) asm volatile("s_waitcnt vmcnt(0)" ::: "memory");
        else        asm volatile("s_waitcnt vmcnt(3)" ::: "memory");
        __builtin_amdgcn_s_barrier();
        if (s < 6) stage(s + 2, (s + 2) % 3);
        compute(s % 3);
    }

    const f32x4 z4 = {0.f, 0.f, 0.f, 0.f};
    half4 idf;
#pragma unroll
    for (int j = 0; j < 4; ++j) idf[j] = (f16)((g * 4 + j == c) ? 1.f : 0.f);

    if (n0 < 512) {
        // Q,K: transpose via identity mfma, store row-major QK[t][512]
#pragma unroll
        for (int mi = 0; mi < 4; ++mi)
#pragma unroll
            for (int nt = 0; nt < 4; ++nt) {
                int n = n0 + wn * 64 + nt * 16 + c;
                float bias = inb[n];
                half4 h;
#pragma unroll
                for (int r = 0; r < 4; ++r) h[r] = (f16)(acc[mi][nt][r] + bias);
                f32x4 t = MFMA16(h, idf, z4);      // C/D-as-A (=T^T) times I -> transposed tile
                half4 o;
#pragma unroll
                for (int r = 0; r < 4; ++r) o[r] = (f16)t[r];
                size_t tok = Mbase + wm * 64 + mi * 16 + c;       // col of transposed tile = m
                *(half4*)(QK + tok * 512 + (n0 + wn * 64 + nt * 16 + g * 4)) = o;
            }
    } else {
        // V: store [win][d][t] directly from C/D (rows = 4 contiguous tokens)
#pragma unroll
        for (int mi = 0; mi < 4; ++mi)
#pragma unroll
            for (int nt = 0; nt < 4; ++nt) {
                int n = n0 + wn * 64 + nt * 16 + c;
                float bias = inb[n];
                half4 h;
#pragma unroll
                for (int r = 0; r < 4; ++r) h[r] = (f16)(acc[mi][nt][r] + bias);
                int d = n - 512;
                size_t tokb = Mbase + wm * 64 + mi * 16;          // window-aligned
                size_t winI = tokb >> 4;
                *(half4*)(VT + winI * 4096 + (size_t)d * 16 + g * 4) = h;
            }
    }
}

// ---------------- k3: attention + out-proj + proj + GELU -> G[t][256] f16 ----------------
// R20->R21: T4+T5 combo. Triple-buffered weight staging (3x16KB), unified 16-iter chunk
// loop (8 wout + 8 wproj), COUNTED vmcnt (never 0 mid-loop): wait only ops newer than
// stage(it) -- stores from it>=8 epilogues count toward vmcnt (in-order retirement), so
// the bound is 4 (it<=8), 8 (9<=it<=14), 4 (it=15). Raw s_barrier; stage(it+2) issued
// AFTER it (barrier certifies compute(it-1) done -> no WAR on buffer (it-1)%3).
// setprio(1) wraps each 32-MFMA cluster (T5: phase role-split now exists).
__global__ __launch_bounds__(256, 2)
void k3_attn(const f16* __restrict__ QK, const f16* __restrict__ VT,
             const f16* __restrict__ wout, const f16* __restrict__ wproj,
             const float* __restrict__ outb, const float* __restrict__ projb,
             f16* __restrict__ G) {
    __shared__ __align__(16) char sm[49152];   // 3 x 16KB weight chunks (k2-geometry image)
    const int tid = threadIdx.x, lane = tid & 63, wv = tid >> 6;   // 4 waves
    const int c = lane & 15, g = lane >> 4;
    const size_t winA = (size_t)blockIdx.x * 8 + wv * 2;
    const size_t winB = winA + 1;
    const f16* qrowA = QK + (winA * 16 + c) * 512;
    const f16* qrowB = QK + (winB * 16 + c) * 512;
    const f32x4 z4 = {0.f, 0.f, 0.f, 0.f};

    auto stageW = [&](int it, int bsel) {
        const f16* img = (it < 8) ? (wout + it * 8192) : (wproj + (it - 8) * 8192);
#pragma unroll
        for (int q2 = 0; q2 < 4; ++q2) {
            int ia = wv * 4 + q2;
            __builtin_amdgcn_global_load_lds(
                (const __attribute__((address_space(1))) unsigned int*)(img + ia * 512 + lane * 8),
                (__attribute__((address_space(3))) unsigned int*)(sm + bsel * 16384 + ia * 1024),
                16, 0, 0);
        }
    };

    stageW(0, 0);
    stageW(1, 1);

    // ---- attention for both windows; pack PV outputs as MFMA32 B-frags ----
    half8 ofpA[4][2], ofpB[4][2];
#pragma unroll
    for (int wsel = 0; wsel < 2; ++wsel) {
        const f16* qrow = wsel ? qrowB : qrowA;
        const size_t wn_ = wsel ? winB : winA;
#pragma unroll
        for (int hq = 0; hq < 4; ++hq) {
            half8 af0 = *(const half8*)(qrow + 256 + hq * 64 + g * 8);
            half8 af1 = *(const half8*)(qrow + 256 + hq * 64 + 32 + g * 8);
            half8 bq0 = *(const half8*)(qrow + hq * 64 + g * 8);
            half8 bq1 = *(const half8*)(qrow + hq * 64 + 32 + g * 8);
            f32x4 sacc = MFMA32(af0, bq0, z4);     // S^T[k_tok][q]
            sacc = MFMA32(af1, bq1, sacc);
            float s0 = sacc[0] * 0.125f, s1 = sacc[1] * 0.125f;
            float s2 = sacc[2] * 0.125f, s3 = sacc[3] * 0.125f;
            float mx = fmaxf(fmaxf(s0, s1), fmaxf(s2, s3));
            mx = fmaxf(mx, __shfl_xor(mx, 16));
            mx = fmaxf(mx, __shfl_xor(mx, 32));
            float p0 = __expf(s0 - mx), p1 = __expf(s1 - mx);
            float p2 = __expf(s2 - mx), p3 = __expf(s3 - mx);
            float sum = p0 + p1 + p2 + p3;
            sum += __shfl_xor(sum, 16);
            sum += __shfl_xor(sum, 32);
            float inv = 1.f / sum;
            half4 pf;
            pf[0] = (f16)(p0 * inv); pf[1] = (f16)(p1 * inv);
            pf[2] = (f16)(p2 * inv); pf[3] = (f16)(p3 * inv);
#pragma unroll
            for (int nt = 0; nt < 4; ++nt) {
                half4 vf = *(const half4*)(VT + wn_ * 4096 + (size_t)(hq * 64 + nt * 16 + c) * 16 + g * 4);
                f32x4 o = MFMA16(vf, pf, z4);      // O^T[d][q]
#pragma unroll
                for (int r = 0; r < 4; ++r) {
                    if (wsel) ofpB[hq][nt >> 1][(nt & 1) * 4 + r] = (f16)o[r];
                    else      ofpA[hq][nt >> 1][(nt & 1) * 4 + r] = (f16)o[r];
                }
            }
        }
    }

    const int rsl = (g ^ ((c >> 1) & 3)) * 16;   // intra-row rotated 16B slot (k2 pattern)
    half8 obpA[8], obpB[8];

    // ---- unified 16-iter pipeline: it 0..7 = out-proj (wout), 8..15 = proj (wproj) ----
#pragma unroll
    for (int it = 0; it < 16; ++it) {
        if (it == 15)     asm volatile("s_waitcnt vmcnt(4)" ::: "memory");
        else if (it >= 9) asm volatile("s_waitcnt vmcnt(8)" ::: "memory");
        else              asm volatile("s_waitcnt vmcnt(4)" ::: "memory");
        __builtin_amdgcn_s_barrier();
        if (it < 14) stageW(it + 2, (it + 2) % 3);
        char* base = sm + (it % 3) * 16384;
        f32x4 aA0 = z4, aA1 = z4, aB0 = z4, aB1 = z4;
        __builtin_amdgcn_s_setprio(1);
        if (it < 8) {
#pragma unroll
            for (int kc = 0; kc < 8; ++kc) {
                half8 w0 = *(half8*)(base + kc * 2048 + c * 64 + rsl);
                aA0 = MFMA32(w0, ofpA[kc >> 1][kc & 1], aA0);
                aB0 = MFMA32(w0, ofpB[kc >> 1][kc & 1], aB0);
                half8 w1 = *(half8*)(base + kc * 2048 + 1024 + c * 64 + rsl);
                aA1 = MFMA32(w1, ofpA[kc >> 1][kc & 1], aA1);
                aB1 = MFMA32(w1, ofpB[kc >> 1][kc & 1], aB1);
            }
        } else {
#pragma unroll
            for (int kc = 0; kc < 8; ++kc) {
                half8 w0 = *(half8*)(base + kc * 2048 + c * 64 + rsl);
                aA0 = MFMA32(w0, obpA[kc], aA0);
                aB0 = MFMA32(w0, obpB[kc], aB0);
                half8 w1 = *(half8*)(base + kc * 2048 + 1024 + c * 64 + rsl);
                aA1 = MFMA32(w1, obpA[kc], aA1);
                aB1 = MFMA32(w1, obpB[kc], aB1);
            }
        }
        __builtin_amdgcn_s_setprio(0);
        if (it < 8) {
            const int ch = it;
            f32x4 b0 = *(const f32x4*)(outb + ch * 32 + g * 4);
            f32x4 b1 = *(const f32x4*)(outb + ch * 32 + 16 + g * 4);
#pragma unroll
            for (int r = 0; r < 4; ++r) {
                obpA[ch][r]     = (f16)(aA0[r] + b0[r]);
                obpA[ch][4 + r] = (f16)(aA1[r] + b1[r]);
                obpB[ch][r]     = (f16)(aB0[r] + b0[r]);
                obpB[ch][4 + r] = (f16)(aB1[r] + b1[r]);
            }
        } else {
            const int pc = it - 8;
            f32x4 b0 = *(const f32x4*)(projb + pc * 32 + g * 4);
            f32x4 b1 = *(const f32x4*)(projb + pc * 32 + 16 + g * 4);
            half4 hA0, hA1, hB0, hB1;
#pragma unroll
            for (int r = 0; r < 4; ++r) {
                hA0[r] = (f16)gelu_f(aA0[r] + b0[r]);
                hA1[r] = (f16)gelu_f(aA1[r] + b1[r]);
                hB0[r] = (f16)gelu_f(aB0[r] + b0[r]);
                hB1[r] = (f16)gelu_f(aB1[r] + b1[r]);
            }
            f16* growA = G + (winA * 16 + c) * 256 + pc * 32;
            *(half4*)(growA + g * 4) = hA0;
            *(half4*)(growA + 16 + g * 4) = hA1;
            f16* growB = G + (winB * 16 + c) * 256 + pc * 32;
            *(half4*)(growB + g * 4) = hB0;
            *(half4*)(growB + 16 + g * 4) = hB1;
        }
    }
}

// ---------------- k4: residual + NCHW scatter, one block per full (bb,h) row ----------------
__global__ __launch_bounds__(256, 8)
void k4_out(const f16* __restrict__ G, const float* __restrict__ feat, float* __restrict__ outp) {
    const int tid = threadIdx.x;
    const int bid = blockIdx.x;            // bb*127 + h
    const int bb = bid / 127, h = bid % 127;
    const int w = tid & 127;               // 0..127 (w==127 masked: pad column)
    const int cq = tid >> 7;               // 0..1
    const bool wok = (w < 127);
    const size_t bbase = (size_t)bb * (256 * 127 * 127);
    const int wi = h >> 2, hh = h & 3;
    const int jh = w >> 5, wl4 = (w >> 2) & 7, e = w & 3;
    const size_t t = ((size_t)((bb * 32 + wi) * 4 + jh)) * 128 + wl4 * 16 + hh * 4 + e;
    const f16* gp = G + t * 256;
    const float* fp = feat + bbase + (size_t)h * 127 + w;
    float* op = outp + bbase + (size_t)h * 127 + w;
#pragma unroll 4
    for (int ci = 0; ci < 32; ++ci) {
        const int ch = ci * 8 + cq * 4;
        if (wok) {
            half4 g4 = *(const half4*)(gp + ch);
#pragma unroll
            for (int j = 0; j < 4; ++j) {
                size_t off = (size_t)(ch + j) * 16129;
                op[off] = fp[off] + (float)g4[j];
            }
        }
    }
}

extern "C" void kernel_launch(void* const* d_in, const int* in_sizes, int n_in,
                              void* d_out, int out_size, void* d_ws, size_t ws_size,
                              hipStream_t stream) {
    const float* feat   = (const float*)d_in[0];
    const float* ln_w   = (const float*)d_in[1];
    const float* ln_b   = (const float*)d_in[2];
    const float* in_w   = (const float*)d_in[3];
    const float* in_b   = (const float*)d_in[4];
    const float* out_w  = (const float*)d_in[5];
    const float* out_b  = (const float*)d_in[6];
    const float* proj_w = (const float*)d_in[7];
    const float* proj_b = (const float*)d_in[8];

    f16* W  = (f16*)d_ws;
    f16* Xb  = W + X0;
    f16* QKb = W + QK0;
    f16* VTb = W + VT0;
    f16* Gb  = Xb;   // reuse X region for G (X dead after k2)

    k0_cast<<<768, 256, 0, stream>>>(in_w, out_w, proj_w, W);
    k1_pack<<<1024, 256, 0, stream>>>(feat, ln_w, ln_b, Xb);
    k2_qkv<<<3072, 512, 0, stream>>>(Xb, W + W_IN0, in_b, QKb, VTb);
    k3_attn<<<1024, 256, 0, stream>>>(QKb, VTb, W + W_OUT0, W + W_PROJ0, out_b, proj_b, Gb);
    k4_out<<<1016, 256, 0, stream>>>(Gb, feat, (float*)d_out);
}